// Round 5
// baseline (707.348 us; speedup 1.0000x reference)
//
#include <hip/hip_runtime.h>
#include <math.h>

#define D 128

typedef float  f32x4  __attribute__((ext_vector_type(4)));
typedef short  bf16x8 __attribute__((ext_vector_type(8)));

__device__ inline unsigned short bf16r(float f) {
    unsigned u = __float_as_uint(f);
    u = (u + 0x7fff + ((u >> 16) & 1)) >> 16;
    return (unsigned short)u;
}
__device__ inline unsigned bf16pair(float a, float b) {
    return (unsigned)bf16r(a) | ((unsigned)bf16r(b) << 16);
}
__device__ inline float bf16lo(unsigned w) { return __uint_as_float(w << 16); }
__device__ inline float bf16hi(unsigned w) { return __uint_as_float(w & 0xffff0000u); }

__device__ inline void unpack8(uint4 w, float* f) {
    f[0] = bf16lo(w.x); f[1] = bf16hi(w.x);
    f[2] = bf16lo(w.y); f[3] = bf16hi(w.y);
    f[4] = bf16lo(w.z); f[5] = bf16hi(w.z);
    f[6] = bf16lo(w.w); f[7] = bf16hi(w.w);
}

// ---------------------------------------------------------------------------
// convert X (fp32) -> bf16 packed pairs.
// ---------------------------------------------------------------------------
__global__ void convert_x(const float* __restrict__ X, unsigned* __restrict__ Xb, int npairs)
{
    int i = blockIdx.x * blockDim.x + threadIdx.x;
    if (i < npairs) {
        float2 v = *(const float2*)&X[2 * i];
        Xb[i] = bf16pair(v.x, v.y);
    }
}

// ---------------------------------------------------------------------------
// convert + transpose 8 weight matrices [k][n] fp32 -> [n][k] bf16.
// ---------------------------------------------------------------------------
__global__ __launch_bounds__(256)
void convert_w(const float* __restrict__ W0, const float* __restrict__ W1,
               const float* __restrict__ W2, const float* __restrict__ W3,
               const float* __restrict__ W4, const float* __restrict__ W5,
               const float* __restrict__ W6, const float* __restrict__ W7,
               unsigned short* __restrict__ Wt)
{
    const float* Ws[8] = {W0, W1, W2, W3, W4, W5, W6, W7};
    const float* W = Ws[blockIdx.x];
    unsigned short* o = Wt + blockIdx.x * 16384;
    for (int i = threadIdx.x; i < 16384; i += 256) {
        int k = i >> 7, c = i & 127;
        o[c * 128 + k] = bf16r(W[i]);
    }
}

// ---------------------------------------------------------------------------
// MFMA GEMM: 128x128 tile, 4 waves, 16x16x32 bf16 MFMA.
// Q,K,V stored bf16 planes; S stored fp32.
// ---------------------------------------------------------------------------
__global__ __launch_bounds__(256)
void gemm_mfma(const unsigned short* __restrict__ Xb, int n,
               const unsigned short* __restrict__ Wtall,
               const float* __restrict__ bq, const float* __restrict__ bk,
               const float* __restrict__ bv, const float* __restrict__ bs,
               unsigned short* __restrict__ Qp, unsigned short* __restrict__ Kp,
               unsigned short* __restrict__ Vp, float* __restrict__ Sb)
{
    const int w = blockIdx.x;
    const int rowBase = blockIdx.y * 128;
    const unsigned short* W = Wtall + w * 16384;
    const float* bias = (w == 0) ? bq : (w == 1) ? bk : (w == 2) ? bv : bs;
    unsigned short* plane = (w == 0) ? Qp : (w == 1) ? Kp : (w == 2) ? Vp : nullptr;

    __shared__ unsigned short Asm[128 * 136];
    __shared__ unsigned short Bsm[128 * 136];

    const int tid  = threadIdx.x;
    const int wave = tid >> 6;
    const int lane = tid & 63;
    const int wr   = wave >> 1;
    const int wc   = wave & 1;
    const int q16  = lane >> 4;
    const int r16  = lane & 15;

    #pragma unroll
    for (int i = 0; i < 8; ++i) {
        int g = tid + 256 * i;
        int m = g >> 4, c = g & 15;
        int row = rowBase + m; if (row >= n) row = n - 1;
        uint4 da = *(const uint4*)(Xb + (size_t)row * 128 + c * 8);
        *(uint4*)&Asm[m * 136 + c * 8] = da;
        uint4 db = *(const uint4*)(W + (size_t)m * 128 + c * 8);
        *(uint4*)&Bsm[m * 136 + c * 8] = db;
    }
    __syncthreads();

    f32x4 acc[4][4];
    #pragma unroll
    for (int mi = 0; mi < 4; ++mi)
        #pragma unroll
        for (int nj = 0; nj < 4; ++nj) acc[mi][nj] = (f32x4)(0.f);

    #pragma unroll
    for (int kc = 0; kc < 4; ++kc) {
        bf16x8 a[4], b[4];
        #pragma unroll
        for (int mi = 0; mi < 4; ++mi)
            a[mi] = *(const bf16x8*)&Asm[(wr * 64 + mi * 16 + r16) * 136 + kc * 32 + q16 * 8];
        #pragma unroll
        for (int nj = 0; nj < 4; ++nj)
            b[nj] = *(const bf16x8*)&Bsm[(wc * 64 + nj * 16 + r16) * 136 + kc * 32 + q16 * 8];
        #pragma unroll
        for (int mi = 0; mi < 4; ++mi)
            #pragma unroll
            for (int nj = 0; nj < 4; ++nj)
                acc[mi][nj] = __builtin_amdgcn_mfma_f32_16x16x32_bf16(a[mi], b[nj], acc[mi][nj], 0, 0, 0);
    }

    #pragma unroll
    for (int nj = 0; nj < 4; ++nj) {
        const int col = wc * 64 + nj * 16 + r16;
        const float bv4 = bias[col];
        #pragma unroll
        for (int mi = 0; mi < 4; ++mi) {
            #pragma unroll
            for (int r = 0; r < 4; ++r) {
                int row = rowBase + wr * 64 + mi * 16 + q16 * 4 + r;
                if (row >= n) continue;
                float val = acc[mi][nj][r] + bv4;
                size_t off2 = (size_t)row * 128 + col;
                if (plane) plane[off2] = bf16r(val);
                else       Sb[off2] = val;
            }
        }
    }
}

// ---------------------------------------------------------------------------
// CSR build: in-degree histogram -> 3-phase parallel exclusive scan -> scatter
// ---------------------------------------------------------------------------
__global__ void degree_hist(const int* __restrict__ dst, int e, int* __restrict__ cnt)
{
    int i = blockIdx.x * blockDim.x + threadIdx.x;
    if (i < e) atomicAdd(&cnt[dst[i]], 1);
}

__global__ __launch_bounds__(256)
void scan_p1(const int* __restrict__ cnt, int n, int* __restrict__ bsum)
{
    __shared__ int sm[256];
    int i = blockIdx.x * 256 + threadIdx.x;
    sm[threadIdx.x] = (i < n) ? cnt[i] : 0;
    __syncthreads();
    #pragma unroll
    for (int off = 128; off > 0; off >>= 1) {
        if (threadIdx.x < off) sm[threadIdx.x] += sm[threadIdx.x + off];
        __syncthreads();
    }
    if (threadIdx.x == 0) bsum[blockIdx.x] = sm[0];
}

__global__ __launch_bounds__(256)
void scan_p2(int* __restrict__ bsum, int nb)
{
    __shared__ int sm[256];
    int v = (threadIdx.x < nb) ? bsum[threadIdx.x] : 0;
    sm[threadIdx.x] = v;
    __syncthreads();
    int acc = v;
    for (int off = 1; off < 256; off <<= 1) {
        int t = (threadIdx.x >= off) ? sm[threadIdx.x - off] : 0;
        __syncthreads();
        acc += t;
        sm[threadIdx.x] = acc;
        __syncthreads();
    }
    if (threadIdx.x < nb) bsum[threadIdx.x] = acc - v;
}

__global__ __launch_bounds__(256)
void scan_p3(const int* __restrict__ cnt, const int* __restrict__ bsum,
             int* __restrict__ row_ptr, int n, int e)
{
    __shared__ int sm[256];
    int i = blockIdx.x * 256 + threadIdx.x;
    int v = (i < n) ? cnt[i] : 0;
    sm[threadIdx.x] = v;
    __syncthreads();
    int acc = v;
    for (int off = 1; off < 256; off <<= 1) {
        int t = (threadIdx.x >= off) ? sm[threadIdx.x - off] : 0;
        __syncthreads();
        acc += t;
        sm[threadIdx.x] = acc;
        __syncthreads();
    }
    if (i < n) row_ptr[i] = bsum[blockIdx.x] + acc - v;
    if (blockIdx.x == 0 && threadIdx.x == 0) row_ptr[n] = e;
}

__global__ void scatter_kernel(const int* __restrict__ src, const int* __restrict__ dst, int e,
                               const int* __restrict__ row_ptr, int* __restrict__ cursor,
                               int* __restrict__ csr_src)
{
    int i = blockIdx.x * blockDim.x + threadIdx.x;
    if (i < e) {
        int d = dst[i];
        int pos = atomicAdd(&cursor[d], 1);
        csr_src[row_ptr[d] + pos] = src[i];
    }
}

// ---------------------------------------------------------------------------
// Degree counting sort (descending): perm lists nodes grouped by degree so
// the 4 nodes sharing a wave have ~equal edge counts (no divergence tax).
// ---------------------------------------------------------------------------
__global__ void bucket_hist(const int* __restrict__ cnt, int n, int* __restrict__ bh)
{
    int i = blockIdx.x * blockDim.x + threadIdx.x;
    if (i < n) atomicAdd(&bh[min(cnt[i], 63)], 1);
}

__global__ void bucket_scan(const int* __restrict__ bh, int* __restrict__ boff)
{
    if (threadIdx.x == 0) {
        int run = 0;
        for (int b = 63; b >= 0; --b) { boff[b] = run; run += bh[b]; }
    }
}

__global__ void bucket_scatter(const int* __restrict__ cnt, int n,
                               const int* __restrict__ boff, int* __restrict__ bcur,
                               int* __restrict__ perm)
{
    int i = blockIdx.x * blockDim.x + threadIdx.x;
    if (i < n) {
        int b = min(cnt[i], 63);
        int pos = boff[b] + atomicAdd(&bcur[b], 1);
        perm[pos] = i;
    }
}

// ---------------------------------------------------------------------------
// Attention: 4 nodes per wave (16 lanes/node, 8 ch/lane).
// head = (lane&15)>>3; reduce = 3 shuffles within 8-lane groups.
// Per wave-iteration: 4 edges, each with one uint4 K + one uint4 V load.
// ---------------------------------------------------------------------------
__global__ __launch_bounds__(256)
void attn(const uint4* __restrict__ Qp, const uint4* __restrict__ Kp,
          const uint4* __restrict__ Vp, const float* __restrict__ S,
          const int* __restrict__ row_ptr, const int* __restrict__ csr_src,
          const int* __restrict__ perm,
          float* __restrict__ outf, uint4* __restrict__ outb,
          int n, int do_relu)
{
    const int wid  = (blockIdx.x * 256 + threadIdx.x) >> 6;
    const int lane = threadIdx.x & 63;
    const int nq   = lane >> 4;
    const int l16  = lane & 15;
    const int nidx = wid * 4 + nq;
    const int node = (nidx < n) ? perm[nidx] : -1;

    float q[8];
    int beg = 0, end = 0;
    if (node >= 0) {
        uint4 qw = Qp[(size_t)node * 16 + l16];
        unpack8(qw, q);
        beg = row_ptr[node];
        end = row_ptr[node + 1];
    }

    float m = -INFINITY, l = 0.f;
    float acc[8] = {0.f, 0.f, 0.f, 0.f, 0.f, 0.f, 0.f, 0.f};

    int i = beg;
    uint4 kw = make_uint4(0, 0, 0, 0), vw = make_uint4(0, 0, 0, 0);
    if (i < end) {
        int s = csr_src[i];
        kw = Kp[(size_t)s * 16 + l16];
        vw = Vp[(size_t)s * 16 + l16];
    }
    while (i < end) {
        uint4 kc = kw, vc = vw;
        if (i + 1 < end) {
            int s2 = csr_src[i + 1];
            kw = Kp[(size_t)s2 * 16 + l16];
            vw = Vp[(size_t)s2 * 16 + l16];
        }
        float kf[8], vf[8];
        unpack8(kc, kf);
        unpack8(vc, vf);
        float part = q[0]*kf[0] + q[1]*kf[1] + q[2]*kf[2] + q[3]*kf[3]
                   + q[4]*kf[4] + q[5]*kf[5] + q[6]*kf[6] + q[7]*kf[7];
        part += __shfl_xor(part, 4, 64);
        part += __shfl_xor(part, 2, 64);
        part += __shfl_xor(part, 1, 64);
        float alpha = part * 0.125f;              // / sqrt(64)
        float mn = fmaxf(m, alpha);
        float corr = __expf(m - mn);              // exp(-inf)=0 first iter
        float p = __expf(alpha - mn);
        l = l * corr + p;
        #pragma unroll
        for (int c2 = 0; c2 < 8; ++c2) acc[c2] = acc[c2] * corr + p * vf[c2];
        m = mn;
        ++i;
    }

    if (node >= 0) {
        float inv = (l > 0.f) ? (1.f / l) : 0.f;
        const float4 s0 = *(const float4*)&S[(size_t)node * 128 + l16 * 8];
        const float4 s1 = *(const float4*)&S[(size_t)node * 128 + l16 * 8 + 4];
        float r[8];
        r[0] = acc[0] * inv + s0.x; r[1] = acc[1] * inv + s0.y;
        r[2] = acc[2] * inv + s0.z; r[3] = acc[3] * inv + s0.w;
        r[4] = acc[4] * inv + s1.x; r[5] = acc[5] * inv + s1.y;
        r[6] = acc[6] * inv + s1.z; r[7] = acc[7] * inv + s1.w;
        if (do_relu) {
            #pragma unroll
            for (int c2 = 0; c2 < 8; ++c2) r[c2] = fmaxf(r[c2], 0.f);
        }
        if (outb) {
            uint4 o;
            o.x = bf16pair(r[0], r[1]); o.y = bf16pair(r[2], r[3]);
            o.z = bf16pair(r[4], r[5]); o.w = bf16pair(r[6], r[7]);
            outb[(size_t)node * 16 + l16] = o;
        } else {
            *(float4*)&outf[(size_t)node * 128 + l16 * 8]     = make_float4(r[0], r[1], r[2], r[3]);
            *(float4*)&outf[(size_t)node * 128 + l16 * 8 + 4] = make_float4(r[4], r[5], r[6], r[7]);
        }
    }
}

// ---------------------------------------------------------------------------
extern "C" void kernel_launch(void* const* d_in, const int* in_sizes, int n_in,
                              void* d_out, int out_size, void* d_ws, size_t ws_size,
                              hipStream_t stream)
{
    const float* x    = (const float*)d_in[0];
    const int*   edge = (const int*)d_in[1];
    const int n = in_sizes[0] / D;
    const int e = in_sizes[1] / 2;
    const int* srcv = edge;
    const int* dstv = edge + e;

    const float* Wq1 = (const float*)d_in[2];  const float* bq1 = (const float*)d_in[3];
    const float* Wk1 = (const float*)d_in[4];  const float* bk1 = (const float*)d_in[5];
    const float* Wv1 = (const float*)d_in[6];  const float* bv1 = (const float*)d_in[7];
    const float* Ws1 = (const float*)d_in[8];  const float* bs1 = (const float*)d_in[9];
    const float* Wq2 = (const float*)d_in[10]; const float* bq2 = (const float*)d_in[11];
    const float* Wk2 = (const float*)d_in[12]; const float* bk2 = (const float*)d_in[13];
    const float* Wv2 = (const float*)d_in[14]; const float* bv2 = (const float*)d_in[15];
    const float* Ws2 = (const float*)d_in[16]; const float* bs2 = (const float*)d_in[17];

    char* wsb = (char*)d_ws;
    size_t off = 0;
    auto alloc = [&](size_t bytes) -> void* {
        void* p = wsb + off;
        off += (bytes + 255) & ~(size_t)255;
        return p;
    };
    unsigned short* Qp = (unsigned short*)alloc((size_t)n * D * sizeof(unsigned short));
    unsigned short* Kp = (unsigned short*)alloc((size_t)n * D * sizeof(unsigned short));
    unsigned short* Vp = (unsigned short*)alloc((size_t)n * D * sizeof(unsigned short));
    float*          Sb = (float*)alloc((size_t)n * D * sizeof(float));
    unsigned short* Xb = (unsigned short*)alloc((size_t)n * D * sizeof(unsigned short));
    unsigned short* Hu = (unsigned short*)alloc((size_t)n * D * sizeof(unsigned short));
    unsigned short* Wt = (unsigned short*)alloc(8 * 16384 * sizeof(unsigned short));
    int* cnt     = (int*)alloc((size_t)n * sizeof(int));
    int* cursor  = (int*)alloc((size_t)n * sizeof(int));
    int* row_ptr = (int*)alloc((size_t)(n + 1) * sizeof(int));
    int* bsum    = (int*)alloc(1024 * sizeof(int));
    int* perm    = (int*)alloc((size_t)n * sizeof(int));
    int* bh      = (int*)alloc(64 * sizeof(int));
    int* bcur    = (int*)alloc(64 * sizeof(int));
    int* boff    = (int*)alloc(64 * sizeof(int));
    int* csr_src = (int*)alloc((size_t)e * sizeof(int));
    (void)ws_size; (void)n_in; (void)out_size;

    const int nb = (n + 255) / 256;

    // ---- dtype conversions ----
    convert_x<<<(n * 64 + 255) / 256, 256, 0, stream>>>(x, (unsigned*)Xb, n * 64);
    convert_w<<<8, 256, 0, stream>>>(Wq1, Wk1, Wv1, Ws1, Wq2, Wk2, Wv2, Ws2, Wt);

    // ---- CSR build + degree sort ----
    hipMemsetAsync(cnt, 0, (size_t)n * sizeof(int), stream);
    hipMemsetAsync(cursor, 0, (size_t)n * sizeof(int), stream);
    hipMemsetAsync(bh, 0, 64 * sizeof(int), stream);
    hipMemsetAsync(bcur, 0, 64 * sizeof(int), stream);
    degree_hist<<<(e + 255) / 256, 256, 0, stream>>>(dstv, e, cnt);
    scan_p1<<<nb, 256, 0, stream>>>(cnt, n, bsum);
    scan_p2<<<1, 256, 0, stream>>>(bsum, nb);
    scan_p3<<<nb, 256, 0, stream>>>(cnt, bsum, row_ptr, n, e);
    bucket_hist<<<nb, 256, 0, stream>>>(cnt, n, bh);
    bucket_scan<<<1, 64, 0, stream>>>(bh, boff);
    bucket_scatter<<<nb, 256, 0, stream>>>(cnt, n, boff, bcur, perm);
    scatter_kernel<<<(e + 255) / 256, 256, 0, stream>>>(srcv, dstv, e, row_ptr, cursor, csr_src);

    const dim3 ggrid(4, (n + 127) / 128);
    const int ablocks = ((n + 3) / 4 + 3) / 4;   // waves = ceil(n/4), 4 waves/block

    // ---- layer 1 ----
    gemm_mfma<<<ggrid, 256, 0, stream>>>(Xb, n, Wt, bq1, bk1, bv1, bs1, Qp, Kp, Vp, Sb);
    attn<<<ablocks, 256, 0, stream>>>((const uint4*)Qp, (const uint4*)Kp, (const uint4*)Vp, Sb,
                                      row_ptr, csr_src, perm, nullptr, (uint4*)Hu, n, 1);

    // ---- layer 2 ----
    gemm_mfma<<<ggrid, 256, 0, stream>>>(Hu, n, Wt + 4 * 16384, bq2, bk2, bv2, bs2, Qp, Kp, Vp, Sb);
    attn<<<ablocks, 256, 0, stream>>>((const uint4*)Qp, (const uint4*)Kp, (const uint4*)Vp, Sb,
                                      row_ptr, csr_src, perm, (float*)d_out, nullptr, n, 0);
}

// Round 6
// 412.513 us; speedup vs baseline: 1.7147x; 1.7147x over previous
//
#include <hip/hip_runtime.h>
#include <math.h>

#define D 128

typedef float  f32x4  __attribute__((ext_vector_type(4)));
typedef short  bf16x8 __attribute__((ext_vector_type(8)));

__device__ inline unsigned short bf16r(float f) {
    unsigned u = __float_as_uint(f);
    u = (u + 0x7fff + ((u >> 16) & 1)) >> 16;
    return (unsigned short)u;
}
__device__ inline unsigned bf16pair(float a, float b) {
    return (unsigned)bf16r(a) | ((unsigned)bf16r(b) << 16);
}
__device__ inline float bf16lo(unsigned w) { return __uint_as_float(w << 16); }
__device__ inline float bf16hi(unsigned w) { return __uint_as_float(w & 0xffff0000u); }

__device__ inline void unpack8(uint4 w, float* f) {
    f[0] = bf16lo(w.x); f[1] = bf16hi(w.x);
    f[2] = bf16lo(w.y); f[3] = bf16hi(w.y);
    f[4] = bf16lo(w.z); f[5] = bf16hi(w.z);
    f[6] = bf16lo(w.w); f[7] = bf16hi(w.w);
}

// ---------------------------------------------------------------------------
// convert X (fp32) -> bf16 packed pairs.
// ---------------------------------------------------------------------------
__global__ void convert_x(const float* __restrict__ X, unsigned* __restrict__ Xb, int npairs)
{
    int i = blockIdx.x * blockDim.x + threadIdx.x;
    if (i < npairs) {
        float2 v = *(const float2*)&X[2 * i];
        Xb[i] = bf16pair(v.x, v.y);
    }
}

// ---------------------------------------------------------------------------
// convert + transpose 8 weight matrices [k][n] fp32 -> [n][k] bf16.
// ---------------------------------------------------------------------------
__global__ __launch_bounds__(256)
void convert_w(const float* __restrict__ W0, const float* __restrict__ W1,
               const float* __restrict__ W2, const float* __restrict__ W3,
               const float* __restrict__ W4, const float* __restrict__ W5,
               const float* __restrict__ W6, const float* __restrict__ W7,
               unsigned short* __restrict__ Wt)
{
    const float* Ws[8] = {W0, W1, W2, W3, W4, W5, W6, W7};
    const float* W = Ws[blockIdx.x];
    unsigned short* o = Wt + blockIdx.x * 16384;
    for (int i = threadIdx.x; i < 16384; i += 256) {
        int k = i >> 7, c = i & 127;
        o[c * 128 + k] = bf16r(W[i]);
    }
}

// ---------------------------------------------------------------------------
// MFMA GEMM: 128x128 tile, 4 waves, 16x16x32 bf16 MFMA.
// Q,K,V stored bf16 planes; S stored fp32.
// ---------------------------------------------------------------------------
__global__ __launch_bounds__(256)
void gemm_mfma(const unsigned short* __restrict__ Xb, int n,
               const unsigned short* __restrict__ Wtall,
               const float* __restrict__ bq, const float* __restrict__ bk,
               const float* __restrict__ bv, const float* __restrict__ bs,
               unsigned short* __restrict__ Qp, unsigned short* __restrict__ Kp,
               unsigned short* __restrict__ Vp, float* __restrict__ Sb)
{
    const int w = blockIdx.x;
    const int rowBase = blockIdx.y * 128;
    const unsigned short* W = Wtall + w * 16384;
    const float* bias = (w == 0) ? bq : (w == 1) ? bk : (w == 2) ? bv : bs;
    unsigned short* plane = (w == 0) ? Qp : (w == 1) ? Kp : (w == 2) ? Vp : nullptr;

    __shared__ unsigned short Asm[128 * 136];
    __shared__ unsigned short Bsm[128 * 136];

    const int tid  = threadIdx.x;
    const int wave = tid >> 6;
    const int lane = tid & 63;
    const int wr   = wave >> 1;
    const int wc   = wave & 1;
    const int q16  = lane >> 4;
    const int r16  = lane & 15;

    #pragma unroll
    for (int i = 0; i < 8; ++i) {
        int g = tid + 256 * i;
        int m = g >> 4, c = g & 15;
        int row = rowBase + m; if (row >= n) row = n - 1;
        uint4 da = *(const uint4*)(Xb + (size_t)row * 128 + c * 8);
        *(uint4*)&Asm[m * 136 + c * 8] = da;
        uint4 db = *(const uint4*)(W + (size_t)m * 128 + c * 8);
        *(uint4*)&Bsm[m * 136 + c * 8] = db;
    }
    __syncthreads();

    f32x4 acc[4][4];
    #pragma unroll
    for (int mi = 0; mi < 4; ++mi)
        #pragma unroll
        for (int nj = 0; nj < 4; ++nj) acc[mi][nj] = (f32x4)(0.f);

    #pragma unroll
    for (int kc = 0; kc < 4; ++kc) {
        bf16x8 a[4], b[4];
        #pragma unroll
        for (int mi = 0; mi < 4; ++mi)
            a[mi] = *(const bf16x8*)&Asm[(wr * 64 + mi * 16 + r16) * 136 + kc * 32 + q16 * 8];
        #pragma unroll
        for (int nj = 0; nj < 4; ++nj)
            b[nj] = *(const bf16x8*)&Bsm[(wc * 64 + nj * 16 + r16) * 136 + kc * 32 + q16 * 8];
        #pragma unroll
        for (int mi = 0; mi < 4; ++mi)
            #pragma unroll
            for (int nj = 0; nj < 4; ++nj)
                acc[mi][nj] = __builtin_amdgcn_mfma_f32_16x16x32_bf16(a[mi], b[nj], acc[mi][nj], 0, 0, 0);
    }

    #pragma unroll
    for (int nj = 0; nj < 4; ++nj) {
        const int col = wc * 64 + nj * 16 + r16;
        const float bv4 = bias[col];
        #pragma unroll
        for (int mi = 0; mi < 4; ++mi) {
            #pragma unroll
            for (int r = 0; r < 4; ++r) {
                int row = rowBase + wr * 64 + mi * 16 + q16 * 4 + r;
                if (row >= n) continue;
                float val = acc[mi][nj][r] + bv4;
                size_t off2 = (size_t)row * 128 + col;
                if (plane) plane[off2] = bf16r(val);
                else       Sb[off2] = val;
            }
        }
    }
}

// ---------------------------------------------------------------------------
// CSR build: in-degree histogram -> 3-phase parallel exclusive scan -> scatter
// ---------------------------------------------------------------------------
__global__ void degree_hist(const int* __restrict__ dst, int e, int* __restrict__ cnt)
{
    int i = blockIdx.x * blockDim.x + threadIdx.x;
    if (i < e) atomicAdd(&cnt[dst[i]], 1);
}

__global__ __launch_bounds__(256)
void scan_p1(const int* __restrict__ cnt, int n, int* __restrict__ bsum)
{
    __shared__ int sm[256];
    int i = blockIdx.x * 256 + threadIdx.x;
    sm[threadIdx.x] = (i < n) ? cnt[i] : 0;
    __syncthreads();
    #pragma unroll
    for (int off = 128; off > 0; off >>= 1) {
        if (threadIdx.x < off) sm[threadIdx.x] += sm[threadIdx.x + off];
        __syncthreads();
    }
    if (threadIdx.x == 0) bsum[blockIdx.x] = sm[0];
}

__global__ __launch_bounds__(256)
void scan_p2(int* __restrict__ bsum, int nb)
{
    __shared__ int sm[256];
    int v = (threadIdx.x < nb) ? bsum[threadIdx.x] : 0;
    sm[threadIdx.x] = v;
    __syncthreads();
    int acc = v;
    for (int off = 1; off < 256; off <<= 1) {
        int t = (threadIdx.x >= off) ? sm[threadIdx.x - off] : 0;
        __syncthreads();
        acc += t;
        sm[threadIdx.x] = acc;
        __syncthreads();
    }
    if (threadIdx.x < nb) bsum[threadIdx.x] = acc - v;
}

__global__ __launch_bounds__(256)
void scan_p3(const int* __restrict__ cnt, const int* __restrict__ bsum,
             int* __restrict__ row_ptr, int n, int e)
{
    __shared__ int sm[256];
    int i = blockIdx.x * 256 + threadIdx.x;
    int v = (i < n) ? cnt[i] : 0;
    sm[threadIdx.x] = v;
    __syncthreads();
    int acc = v;
    for (int off = 1; off < 256; off <<= 1) {
        int t = (threadIdx.x >= off) ? sm[threadIdx.x - off] : 0;
        __syncthreads();
        acc += t;
        sm[threadIdx.x] = acc;
        __syncthreads();
    }
    if (i < n) row_ptr[i] = bsum[blockIdx.x] + acc - v;
    if (blockIdx.x == 0 && threadIdx.x == 0) row_ptr[n] = e;
}

__global__ void scatter_kernel(const int* __restrict__ src, const int* __restrict__ dst, int e,
                               const int* __restrict__ row_ptr, int* __restrict__ cursor,
                               int* __restrict__ csr_src)
{
    int i = blockIdx.x * blockDim.x + threadIdx.x;
    if (i < e) {
        int d = dst[i];
        int pos = atomicAdd(&cursor[d], 1);
        csr_src[row_ptr[d] + pos] = src[i];
    }
}

// ---------------------------------------------------------------------------
// Degree counting sort (descending), two-level atomics: per-block LDS
// histogram (fast LDS atomics), then <=64 global atomics per block.
// 50k contended global atomics on 64 lines was 153 us (R4 regression).
// ---------------------------------------------------------------------------
__global__ __launch_bounds__(256)
void bucket_hist(const int* __restrict__ cnt, int n, int* __restrict__ bh)
{
    __shared__ int lh[64];
    if (threadIdx.x < 64) lh[threadIdx.x] = 0;
    __syncthreads();
    int i = blockIdx.x * 256 + threadIdx.x;
    if (i < n) atomicAdd(&lh[min(cnt[i], 63)], 1);
    __syncthreads();
    if (threadIdx.x < 64 && lh[threadIdx.x] > 0)
        atomicAdd(&bh[threadIdx.x], lh[threadIdx.x]);
}

__global__ void bucket_scan(const int* __restrict__ bh, int* __restrict__ boff)
{
    if (threadIdx.x == 0) {
        int run = 0;
        for (int b = 63; b >= 0; --b) { boff[b] = run; run += bh[b]; }
    }
}

__global__ __launch_bounds__(256)
void bucket_scatter(const int* __restrict__ cnt, int n,
                    const int* __restrict__ boff, int* __restrict__ bcur,
                    int* __restrict__ perm)
{
    __shared__ int lh[64];
    __shared__ int lbase[64];
    if (threadIdx.x < 64) lh[threadIdx.x] = 0;
    __syncthreads();
    int i = blockIdx.x * 256 + threadIdx.x;
    int b = 0, local = 0;
    if (i < n) {
        b = min(cnt[i], 63);
        local = atomicAdd(&lh[b], 1);          // LDS atomic: block-local rank
    }
    __syncthreads();
    if (threadIdx.x < 64 && lh[threadIdx.x] > 0)
        lbase[threadIdx.x] = atomicAdd(&bcur[threadIdx.x], lh[threadIdx.x]);
    __syncthreads();
    if (i < n) perm[boff[b] + lbase[b] + local] = i;
}

// ---------------------------------------------------------------------------
// Attention: 4 nodes per wave (16 lanes/node, 8 ch/lane).
// head = (lane&15)>>3; reduce = 3 shuffles within 8-lane groups.
// Per wave-iteration: 4 edges, each with one uint4 K + one uint4 V load.
// ---------------------------------------------------------------------------
__global__ __launch_bounds__(256)
void attn(const uint4* __restrict__ Qp, const uint4* __restrict__ Kp,
          const uint4* __restrict__ Vp, const float* __restrict__ S,
          const int* __restrict__ row_ptr, const int* __restrict__ csr_src,
          const int* __restrict__ perm,
          float* __restrict__ outf, uint4* __restrict__ outb,
          int n, int do_relu)
{
    const int wid  = (blockIdx.x * 256 + threadIdx.x) >> 6;
    const int lane = threadIdx.x & 63;
    const int nq   = lane >> 4;
    const int l16  = lane & 15;
    const int nidx = wid * 4 + nq;
    const int node = (nidx < n) ? perm[nidx] : -1;

    float q[8];
    int beg = 0, end = 0;
    if (node >= 0) {
        uint4 qw = Qp[(size_t)node * 16 + l16];
        unpack8(qw, q);
        beg = row_ptr[node];
        end = row_ptr[node + 1];
    }

    float m = -INFINITY, l = 0.f;
    float acc[8] = {0.f, 0.f, 0.f, 0.f, 0.f, 0.f, 0.f, 0.f};

    int i = beg;
    uint4 kw = make_uint4(0, 0, 0, 0), vw = make_uint4(0, 0, 0, 0);
    if (i < end) {
        int s = csr_src[i];
        kw = Kp[(size_t)s * 16 + l16];
        vw = Vp[(size_t)s * 16 + l16];
    }
    while (i < end) {
        uint4 kc = kw, vc = vw;
        if (i + 1 < end) {
            int s2 = csr_src[i + 1];
            kw = Kp[(size_t)s2 * 16 + l16];
            vw = Vp[(size_t)s2 * 16 + l16];
        }
        float kf[8], vf[8];
        unpack8(kc, kf);
        unpack8(vc, vf);
        float part = q[0]*kf[0] + q[1]*kf[1] + q[2]*kf[2] + q[3]*kf[3]
                   + q[4]*kf[4] + q[5]*kf[5] + q[6]*kf[6] + q[7]*kf[7];
        part += __shfl_xor(part, 4, 64);
        part += __shfl_xor(part, 2, 64);
        part += __shfl_xor(part, 1, 64);
        float alpha = part * 0.125f;              // / sqrt(64)
        float mn = fmaxf(m, alpha);
        float corr = __expf(m - mn);              // exp(-inf)=0 first iter
        float p = __expf(alpha - mn);
        l = l * corr + p;
        #pragma unroll
        for (int c2 = 0; c2 < 8; ++c2) acc[c2] = acc[c2] * corr + p * vf[c2];
        m = mn;
        ++i;
    }

    if (node >= 0) {
        float inv = (l > 0.f) ? (1.f / l) : 0.f;
        const float4 s0 = *(const float4*)&S[(size_t)node * 128 + l16 * 8];
        const float4 s1 = *(const float4*)&S[(size_t)node * 128 + l16 * 8 + 4];
        float r[8];
        r[0] = acc[0] * inv + s0.x; r[1] = acc[1] * inv + s0.y;
        r[2] = acc[2] * inv + s0.z; r[3] = acc[3] * inv + s0.w;
        r[4] = acc[4] * inv + s1.x; r[5] = acc[5] * inv + s1.y;
        r[6] = acc[6] * inv + s1.z; r[7] = acc[7] * inv + s1.w;
        if (do_relu) {
            #pragma unroll
            for (int c2 = 0; c2 < 8; ++c2) r[c2] = fmaxf(r[c2], 0.f);
        }
        if (outb) {
            uint4 o;
            o.x = bf16pair(r[0], r[1]); o.y = bf16pair(r[2], r[3]);
            o.z = bf16pair(r[4], r[5]); o.w = bf16pair(r[6], r[7]);
            outb[(size_t)node * 16 + l16] = o;
        } else {
            *(float4*)&outf[(size_t)node * 128 + l16 * 8]     = make_float4(r[0], r[1], r[2], r[3]);
            *(float4*)&outf[(size_t)node * 128 + l16 * 8 + 4] = make_float4(r[4], r[5], r[6], r[7]);
        }
    }
}

// ---------------------------------------------------------------------------
extern "C" void kernel_launch(void* const* d_in, const int* in_sizes, int n_in,
                              void* d_out, int out_size, void* d_ws, size_t ws_size,
                              hipStream_t stream)
{
    const float* x    = (const float*)d_in[0];
    const int*   edge = (const int*)d_in[1];
    const int n = in_sizes[0] / D;
    const int e = in_sizes[1] / 2;
    const int* srcv = edge;
    const int* dstv = edge + e;

    const float* Wq1 = (const float*)d_in[2];  const float* bq1 = (const float*)d_in[3];
    const float* Wk1 = (const float*)d_in[4];  const float* bk1 = (const float*)d_in[5];
    const float* Wv1 = (const float*)d_in[6];  const float* bv1 = (const float*)d_in[7];
    const float* Ws1 = (const float*)d_in[8];  const float* bs1 = (const float*)d_in[9];
    const float* Wq2 = (const float*)d_in[10]; const float* bq2 = (const float*)d_in[11];
    const float* Wk2 = (const float*)d_in[12]; const float* bk2 = (const float*)d_in[13];
    const float* Wv2 = (const float*)d_in[14]; const float* bv2 = (const float*)d_in[15];
    const float* Ws2 = (const float*)d_in[16]; const float* bs2 = (const float*)d_in[17];

    char* wsb = (char*)d_ws;
    size_t off = 0;
    auto alloc = [&](size_t bytes) -> void* {
        void* p = wsb + off;
        off += (bytes + 255) & ~(size_t)255;
        return p;
    };
    unsigned short* Qp = (unsigned short*)alloc((size_t)n * D * sizeof(unsigned short));
    unsigned short* Kp = (unsigned short*)alloc((size_t)n * D * sizeof(unsigned short));
    unsigned short* Vp = (unsigned short*)alloc((size_t)n * D * sizeof(unsigned short));
    float*          Sb = (float*)alloc((size_t)n * D * sizeof(float));
    unsigned short* Xb = (unsigned short*)alloc((size_t)n * D * sizeof(unsigned short));
    unsigned short* Hu = (unsigned short*)alloc((size_t)n * D * sizeof(unsigned short));
    unsigned short* Wt = (unsigned short*)alloc(8 * 16384 * sizeof(unsigned short));
    int* cnt     = (int*)alloc((size_t)n * sizeof(int));
    int* cursor  = (int*)alloc((size_t)n * sizeof(int));
    int* row_ptr = (int*)alloc((size_t)(n + 1) * sizeof(int));
    int* bsum    = (int*)alloc(1024 * sizeof(int));
    int* perm    = (int*)alloc((size_t)n * sizeof(int));
    int* bh      = (int*)alloc(64 * sizeof(int));
    int* bcur    = (int*)alloc(64 * sizeof(int));
    int* boff    = (int*)alloc(64 * sizeof(int));
    int* csr_src = (int*)alloc((size_t)e * sizeof(int));
    (void)ws_size; (void)n_in; (void)out_size;

    const int nb = (n + 255) / 256;

    // ---- dtype conversions ----
    convert_x<<<(n * 64 + 255) / 256, 256, 0, stream>>>(x, (unsigned*)Xb, n * 64);
    convert_w<<<8, 256, 0, stream>>>(Wq1, Wk1, Wv1, Ws1, Wq2, Wk2, Wv2, Ws2, Wt);

    // ---- CSR build + degree sort ----
    hipMemsetAsync(cnt, 0, (size_t)n * sizeof(int), stream);
    hipMemsetAsync(cursor, 0, (size_t)n * sizeof(int), stream);
    hipMemsetAsync(bh, 0, 64 * sizeof(int), stream);
    hipMemsetAsync(bcur, 0, 64 * sizeof(int), stream);
    degree_hist<<<(e + 255) / 256, 256, 0, stream>>>(dstv, e, cnt);
    scan_p1<<<nb, 256, 0, stream>>>(cnt, n, bsum);
    scan_p2<<<1, 256, 0, stream>>>(bsum, nb);
    scan_p3<<<nb, 256, 0, stream>>>(cnt, bsum, row_ptr, n, e);
    bucket_hist<<<nb, 256, 0, stream>>>(cnt, n, bh);
    bucket_scan<<<1, 64, 0, stream>>>(bh, boff);
    bucket_scatter<<<nb, 256, 0, stream>>>(cnt, n, boff, bcur, perm);
    scatter_kernel<<<(e + 255) / 256, 256, 0, stream>>>(srcv, dstv, e, row_ptr, cursor, csr_src);

    const dim3 ggrid(4, (n + 127) / 128);
    const int ablocks = ((n + 3) / 4 + 3) / 4;   // waves = ceil(n/4), 4 waves/block

    // ---- layer 1 ----
    gemm_mfma<<<ggrid, 256, 0, stream>>>(Xb, n, Wt, bq1, bk1, bv1, bs1, Qp, Kp, Vp, Sb);
    attn<<<ablocks, 256, 0, stream>>>((const uint4*)Qp, (const uint4*)Kp, (const uint4*)Vp, Sb,
                                      row_ptr, csr_src, perm, nullptr, (uint4*)Hu, n, 1);

    // ---- layer 2 ----
    gemm_mfma<<<ggrid, 256, 0, stream>>>(Hu, n, Wt + 4 * 16384, bq2, bk2, bv2, bs2, Qp, Kp, Vp, Sb);
    attn<<<ablocks, 256, 0, stream>>>((const uint4*)Qp, (const uint4*)Kp, (const uint4*)Vp, Sb,
                                      row_ptr, csr_src, perm, (float*)d_out, nullptr, n, 0);
}

// Round 7
// 357.140 us; speedup vs baseline: 1.9806x; 1.1550x over previous
//
#include <hip/hip_runtime.h>
#include <math.h>

#define D 128

typedef float  f32x4  __attribute__((ext_vector_type(4)));
typedef short  bf16x8 __attribute__((ext_vector_type(8)));

__device__ inline unsigned short bf16r(float f) {
    unsigned u = __float_as_uint(f);
    u = (u + 0x7fff + ((u >> 16) & 1)) >> 16;
    return (unsigned short)u;
}
__device__ inline unsigned bf16pair(float a, float b) {
    return (unsigned)bf16r(a) | ((unsigned)bf16r(b) << 16);
}
__device__ inline float bf16lo(unsigned w) { return __uint_as_float(w << 16); }
__device__ inline float bf16hi(unsigned w) { return __uint_as_float(w & 0xffff0000u); }

__device__ inline void unpack8(uint4 w, float* f) {
    f[0] = bf16lo(w.x); f[1] = bf16hi(w.x);
    f[2] = bf16lo(w.y); f[3] = bf16hi(w.y);
    f[4] = bf16lo(w.z); f[5] = bf16hi(w.z);
    f[6] = bf16lo(w.w); f[7] = bf16hi(w.w);
}

// ---------------------------------------------------------------------------
// prep: fused convert_x + zero(cnt,cursor) + convert_w + zero(bh,bcur).
// Block role chosen by blockIdx range (saves 5 dispatch replays).
// ---------------------------------------------------------------------------
__global__ __launch_bounds__(256)
void prep(const float* __restrict__ X, unsigned* __restrict__ Xb, int npairs,
          const float* __restrict__ W0, const float* __restrict__ W1,
          const float* __restrict__ W2, const float* __restrict__ W3,
          const float* __restrict__ W4, const float* __restrict__ W5,
          const float* __restrict__ W6, const float* __restrict__ W7,
          unsigned short* __restrict__ Wt,
          int* __restrict__ cnt, int* __restrict__ cursor,
          int* __restrict__ bh, int* __restrict__ bcur, int n)
{
    const int nxb = (npairs + 255) >> 8;
    const int nz  = (n + 255) >> 8;
    const int b = blockIdx.x;
    if (b < nxb) {
        int i = b * 256 + threadIdx.x;
        if (i < npairs) {
            float2 v = *(const float2*)&X[2 * i];
            Xb[i] = bf16pair(v.x, v.y);
        }
    } else if (b < nxb + nz) {
        int i = (b - nxb) * 256 + threadIdx.x;
        if (i < n) { cnt[i] = 0; cursor[i] = 0; }
    } else if (b < nxb + nz + 8) {
        int wi = b - nxb - nz;
        const float* Ws[8] = {W0, W1, W2, W3, W4, W5, W6, W7};
        const float* W = Ws[wi];
        unsigned short* o = Wt + wi * 16384;
        for (int i = threadIdx.x; i < 16384; i += 256) {
            int k = i >> 7, c = i & 127;
            o[c * 128 + k] = bf16r(W[i]);
        }
    } else {
        if (threadIdx.x < 64) { bh[threadIdx.x] = 0; bcur[threadIdx.x] = 0; }
    }
}

// ---------------------------------------------------------------------------
// MFMA GEMM v2: A-tile only in LDS (34.8 KB -> 4 blocks/CU); B fragments
// loaded straight from L2-hot Wt with per-kc register double-buffer.
// Epilogue: C round-trips through the dead A-tile LDS (stride 132, 2-way
// free) and stores coalesced 16B bf16 chunks. All outputs bf16 planes.
// ---------------------------------------------------------------------------
__global__ __launch_bounds__(256)
void gemm_mfma(const unsigned short* __restrict__ Xb, int n,
               const unsigned short* __restrict__ Wtall,
               const float* __restrict__ bq, const float* __restrict__ bk,
               const float* __restrict__ bv, const float* __restrict__ bs,
               unsigned short* __restrict__ Qp, unsigned short* __restrict__ Kp,
               unsigned short* __restrict__ Vp, unsigned short* __restrict__ Sp)
{
    const int w = blockIdx.x;
    const int rowBase = blockIdx.y * 128;
    const unsigned short* W = Wtall + w * 16384;
    const float* bias = (w == 0) ? bq : (w == 1) ? bk : (w == 2) ? bv : bs;
    unsigned short* plane = (w == 0) ? Qp : (w == 1) ? Kp : (w == 2) ? Vp : Sp;

    __shared__ unsigned short Asm[128 * 136];

    const int tid  = threadIdx.x;
    const int wave = tid >> 6;
    const int lane = tid & 63;
    const int wr   = wave >> 1;
    const int wc   = wave & 1;
    const int q16  = lane >> 4;
    const int r16  = lane & 15;

    // stage A tile into LDS (8 x 16B per thread)
    #pragma unroll
    for (int i = 0; i < 8; ++i) {
        int g = tid + 256 * i;
        int m = g >> 4, c = g & 15;
        int row = rowBase + m; if (row >= n) row = n - 1;
        uint4 da = *(const uint4*)(Xb + (size_t)row * 128 + c * 8);
        *(uint4*)&Asm[m * 136 + c * 8] = da;
    }

    // B fragment base: this lane covers col = wc*64 + nj*16 + r16
    const unsigned short* Wbase = W + (size_t)(wc * 64 + r16) * 128 + q16 * 8;
    bf16x8 bcur[4], bnxt[4];
    #pragma unroll
    for (int nj = 0; nj < 4; ++nj)
        bcur[nj] = *(const bf16x8*)(Wbase + nj * 16 * 128);

    __syncthreads();

    f32x4 acc[4][4];
    #pragma unroll
    for (int mi = 0; mi < 4; ++mi)
        #pragma unroll
        for (int nj = 0; nj < 4; ++nj) acc[mi][nj] = (f32x4)(0.f);

    #pragma unroll
    for (int kc = 0; kc < 4; ++kc) {
        if (kc < 3) {
            #pragma unroll
            for (int nj = 0; nj < 4; ++nj)
                bnxt[nj] = *(const bf16x8*)(Wbase + nj * 16 * 128 + (kc + 1) * 32);
        }
        bf16x8 a[4];
        #pragma unroll
        for (int mi = 0; mi < 4; ++mi)
            a[mi] = *(const bf16x8*)&Asm[(wr * 64 + mi * 16 + r16) * 136 + kc * 32 + q16 * 8];
        #pragma unroll
        for (int mi = 0; mi < 4; ++mi)
            #pragma unroll
            for (int nj = 0; nj < 4; ++nj)
                acc[mi][nj] = __builtin_amdgcn_mfma_f32_16x16x32_bf16(a[mi], bcur[nj], acc[mi][nj], 0, 0, 0);
        #pragma unroll
        for (int nj = 0; nj < 4; ++nj) bcur[nj] = bnxt[nj];
    }

    // ---- epilogue: C -> LDS (bf16, stride 132) -> coalesced global ----
    __syncthreads();
    #pragma unroll
    for (int nj = 0; nj < 4; ++nj) {
        const int col = wc * 64 + nj * 16 + r16;
        const float bias_c = bias[col];
        #pragma unroll
        for (int mi = 0; mi < 4; ++mi) {
            const int rbase = wr * 64 + mi * 16 + q16 * 4;
            #pragma unroll
            for (int r = 0; r < 4; ++r)
                Asm[(rbase + r) * 132 + col] = bf16r(acc[mi][nj][r] + bias_c);
        }
    }
    __syncthreads();
    #pragma unroll
    for (int i = 0; i < 8; ++i) {
        int g = tid + 256 * i;
        int m = g >> 4, c = g & 15;
        int row = rowBase + m;
        if (row < n) {
            uint4 d2 = *(const uint4*)&Asm[m * 132 + c * 8];
            *(uint4*)(plane + (size_t)row * 128 + c * 8) = d2;
        }
    }
}

// ---------------------------------------------------------------------------
// CSR build + degree sort (fused kernels)
// ---------------------------------------------------------------------------
__global__ void degree_hist(const int* __restrict__ dst, int e, int* __restrict__ cnt)
{
    int i = blockIdx.x * blockDim.x + threadIdx.x;
    if (i < e) atomicAdd(&cnt[dst[i]], 1);
}

// scan phase 1 + bucket histogram (both consume cnt)
__global__ __launch_bounds__(256)
void scan_hist(const int* __restrict__ cnt, int n, int* __restrict__ bsum, int* __restrict__ bh)
{
    __shared__ int sm[256];
    __shared__ int lh[64];
    if (threadIdx.x < 64) lh[threadIdx.x] = 0;
    int i = blockIdx.x * 256 + threadIdx.x;
    int v = (i < n) ? cnt[i] : 0;
    sm[threadIdx.x] = v;
    __syncthreads();
    if (i < n) atomicAdd(&lh[min(v, 63)], 1);
    #pragma unroll
    for (int off = 128; off > 0; off >>= 1) {
        if (threadIdx.x < off) sm[threadIdx.x] += sm[threadIdx.x + off];
        __syncthreads();
    }
    if (threadIdx.x == 0) bsum[blockIdx.x] = sm[0];
    if (threadIdx.x < 64 && lh[threadIdx.x] > 0)
        atomicAdd(&bh[threadIdx.x], lh[threadIdx.x]);
}

// scan of block sums + bucket offsets (single block)
__global__ __launch_bounds__(256)
void scan2(int* __restrict__ bsum, int nb, const int* __restrict__ bh, int* __restrict__ boff)
{
    __shared__ int sm[256];
    int v = (threadIdx.x < nb) ? bsum[threadIdx.x] : 0;
    sm[threadIdx.x] = v;
    __syncthreads();
    int acc = v;
    for (int off = 1; off < 256; off <<= 1) {
        int t = (threadIdx.x >= off) ? sm[threadIdx.x - off] : 0;
        __syncthreads();
        acc += t;
        sm[threadIdx.x] = acc;
        __syncthreads();
    }
    if (threadIdx.x < nb) bsum[threadIdx.x] = acc - v;
    if (threadIdx.x == 0) {
        int run = 0;
        for (int b = 63; b >= 0; --b) { boff[b] = run; run += bh[b]; }
    }
}

// scan phase 3 (row_ptr) + bucket scatter (perm), two-level atomics
__global__ __launch_bounds__(256)
void scan3_scatter(const int* __restrict__ cnt, const int* __restrict__ bsum,
                   int* __restrict__ row_ptr, int n, int e,
                   const int* __restrict__ boff, int* __restrict__ bcur,
                   int* __restrict__ perm)
{
    __shared__ int sm[256];
    __shared__ int lh[64];
    __shared__ int lbase[64];
    if (threadIdx.x < 64) lh[threadIdx.x] = 0;
    __syncthreads();
    int i = blockIdx.x * 256 + threadIdx.x;
    int v = (i < n) ? cnt[i] : 0;
    sm[threadIdx.x] = v;
    int b = 0, local = 0;
    if (i < n) {
        b = min(v, 63);
        local = atomicAdd(&lh[b], 1);
    }
    __syncthreads();
    int acc = v;
    for (int off = 1; off < 256; off <<= 1) {
        int t = (threadIdx.x >= off) ? sm[threadIdx.x - off] : 0;
        __syncthreads();
        acc += t;
        sm[threadIdx.x] = acc;
        __syncthreads();
    }
    if (i < n) row_ptr[i] = bsum[blockIdx.x] + acc - v;
    if (blockIdx.x == 0 && threadIdx.x == 0) row_ptr[n] = e;
    if (threadIdx.x < 64 && lh[threadIdx.x] > 0)
        lbase[threadIdx.x] = atomicAdd(&bcur[threadIdx.x], lh[threadIdx.x]);
    __syncthreads();
    if (i < n) perm[boff[b] + lbase[b] + local] = i;
}

__global__ void edge_scatter(const int* __restrict__ src, const int* __restrict__ dst, int e,
                             const int* __restrict__ row_ptr, int* __restrict__ cursor,
                             int* __restrict__ csr_src)
{
    int i = blockIdx.x * blockDim.x + threadIdx.x;
    if (i < e) {
        int d = dst[i];
        int pos = atomicAdd(&cursor[d], 1);
        csr_src[row_ptr[d] + pos] = src[i];
    }
}

// ---------------------------------------------------------------------------
// Attention: 4 nodes per wave (16 lanes/node, 8 ch/lane), degree-sorted perm.
// Per edge: one uint4 K + one uint4 V load; 3-shuffle reduce; online softmax.
// S read as bf16 plane. Output bf16 (layer 1) or fp32 (final).
// ---------------------------------------------------------------------------
__global__ __launch_bounds__(256)
void attn(const uint4* __restrict__ Qp, const uint4* __restrict__ Kp,
          const uint4* __restrict__ Vp, const uint4* __restrict__ Sp,
          const int* __restrict__ row_ptr, const int* __restrict__ csr_src,
          const int* __restrict__ perm,
          float* __restrict__ outf, uint4* __restrict__ outb,
          int n, int do_relu)
{
    const int wid  = (blockIdx.x * 256 + threadIdx.x) >> 6;
    const int lane = threadIdx.x & 63;
    const int nq   = lane >> 4;
    const int l16  = lane & 15;
    const int nidx = wid * 4 + nq;
    const int node = (nidx < n) ? perm[nidx] : -1;

    float q[8];
    int beg = 0, end = 0;
    if (node >= 0) {
        uint4 qw = Qp[(size_t)node * 16 + l16];
        unpack8(qw, q);
        beg = row_ptr[node];
        end = row_ptr[node + 1];
    }

    float m = -INFINITY, l = 0.f;
    float acc[8] = {0.f, 0.f, 0.f, 0.f, 0.f, 0.f, 0.f, 0.f};

    int i = beg;
    uint4 kw = make_uint4(0, 0, 0, 0), vw = make_uint4(0, 0, 0, 0);
    if (i < end) {
        int s = csr_src[i];
        kw = Kp[(size_t)s * 16 + l16];
        vw = Vp[(size_t)s * 16 + l16];
    }
    while (i < end) {
        uint4 kc = kw, vc = vw;
        if (i + 1 < end) {
            int s2 = csr_src[i + 1];
            kw = Kp[(size_t)s2 * 16 + l16];
            vw = Vp[(size_t)s2 * 16 + l16];
        }
        float kf[8], vf[8];
        unpack8(kc, kf);
        unpack8(vc, vf);
        float part = q[0]*kf[0] + q[1]*kf[1] + q[2]*kf[2] + q[3]*kf[3]
                   + q[4]*kf[4] + q[5]*kf[5] + q[6]*kf[6] + q[7]*kf[7];
        part += __shfl_xor(part, 4, 64);
        part += __shfl_xor(part, 2, 64);
        part += __shfl_xor(part, 1, 64);
        float alpha = part * 0.125f;              // / sqrt(64)
        float mn = fmaxf(m, alpha);
        float corr = __expf(m - mn);              // exp(-inf)=0 first iter
        float p = __expf(alpha - mn);
        l = l * corr + p;
        #pragma unroll
        for (int c2 = 0; c2 < 8; ++c2) acc[c2] = acc[c2] * corr + p * vf[c2];
        m = mn;
        ++i;
    }

    if (node >= 0) {
        float inv = (l > 0.f) ? (1.f / l) : 0.f;
        float sv[8];
        unpack8(Sp[(size_t)node * 16 + l16], sv);
        float r[8];
        #pragma unroll
        for (int c2 = 0; c2 < 8; ++c2) r[c2] = acc[c2] * inv + sv[c2];
        if (do_relu) {
            #pragma unroll
            for (int c2 = 0; c2 < 8; ++c2) r[c2] = fmaxf(r[c2], 0.f);
        }
        if (outb) {
            uint4 o;
            o.x = bf16pair(r[0], r[1]); o.y = bf16pair(r[2], r[3]);
            o.z = bf16pair(r[4], r[5]); o.w = bf16pair(r[6], r[7]);
            outb[(size_t)node * 16 + l16] = o;
        } else {
            *(float4*)&outf[(size_t)node * 128 + l16 * 8]     = make_float4(r[0], r[1], r[2], r[3]);
            *(float4*)&outf[(size_t)node * 128 + l16 * 8 + 4] = make_float4(r[4], r[5], r[6], r[7]);
        }
    }
}

// ---------------------------------------------------------------------------
extern "C" void kernel_launch(void* const* d_in, const int* in_sizes, int n_in,
                              void* d_out, int out_size, void* d_ws, size_t ws_size,
                              hipStream_t stream)
{
    const float* x    = (const float*)d_in[0];
    const int*   edge = (const int*)d_in[1];
    const int n = in_sizes[0] / D;
    const int e = in_sizes[1] / 2;
    const int* srcv = edge;
    const int* dstv = edge + e;

    const float* Wq1 = (const float*)d_in[2];  const float* bq1 = (const float*)d_in[3];
    const float* Wk1 = (const float*)d_in[4];  const float* bk1 = (const float*)d_in[5];
    const float* Wv1 = (const float*)d_in[6];  const float* bv1 = (const float*)d_in[7];
    const float* Ws1 = (const float*)d_in[8];  const float* bs1 = (const float*)d_in[9];
    const float* Wq2 = (const float*)d_in[10]; const float* bq2 = (const float*)d_in[11];
    const float* Wk2 = (const float*)d_in[12]; const float* bk2 = (const float*)d_in[13];
    const float* Wv2 = (const float*)d_in[14]; const float* bv2 = (const float*)d_in[15];
    const float* Ws2 = (const float*)d_in[16]; const float* bs2 = (const float*)d_in[17];

    char* wsb = (char*)d_ws;
    size_t off = 0;
    auto alloc = [&](size_t bytes) -> void* {
        void* p = wsb + off;
        off += (bytes + 255) & ~(size_t)255;
        return p;
    };
    unsigned short* Qp = (unsigned short*)alloc((size_t)n * D * sizeof(unsigned short));
    unsigned short* Kp = (unsigned short*)alloc((size_t)n * D * sizeof(unsigned short));
    unsigned short* Vp = (unsigned short*)alloc((size_t)n * D * sizeof(unsigned short));
    unsigned short* Sp = (unsigned short*)alloc((size_t)n * D * sizeof(unsigned short));
    unsigned short* Xb = (unsigned short*)alloc((size_t)n * D * sizeof(unsigned short));
    unsigned short* Hu = (unsigned short*)alloc((size_t)n * D * sizeof(unsigned short));
    unsigned short* Wt = (unsigned short*)alloc(8 * 16384 * sizeof(unsigned short));
    int* cnt     = (int*)alloc((size_t)n * sizeof(int));
    int* cursor  = (int*)alloc((size_t)n * sizeof(int));
    int* row_ptr = (int*)alloc((size_t)(n + 1) * sizeof(int));
    int* bsum    = (int*)alloc(1024 * sizeof(int));
    int* perm    = (int*)alloc((size_t)n * sizeof(int));
    int* bh      = (int*)alloc(64 * sizeof(int));
    int* bcur    = (int*)alloc(64 * sizeof(int));
    int* boff    = (int*)alloc(64 * sizeof(int));
    int* csr_src = (int*)alloc((size_t)e * sizeof(int));
    (void)ws_size; (void)n_in; (void)out_size;

    const int nb  = (n + 255) / 256;
    const int npairs = n * 64;
    const int nprep  = (npairs + 255) / 256 + nb + 8 + 1;

    // ---- fused init: convert X, convert W, zero counters ----
    prep<<<nprep, 256, 0, stream>>>(x, (unsigned*)Xb, npairs,
        Wq1, Wk1, Wv1, Ws1, Wq2, Wk2, Wv2, Ws2, Wt, cnt, cursor, bh, bcur, n);

    // ---- CSR build + degree sort ----
    degree_hist<<<(e + 255) / 256, 256, 0, stream>>>(dstv, e, cnt);
    scan_hist<<<nb, 256, 0, stream>>>(cnt, n, bsum, bh);
    scan2<<<1, 256, 0, stream>>>(bsum, nb, bh, boff);
    scan3_scatter<<<nb, 256, 0, stream>>>(cnt, bsum, row_ptr, n, e, boff, bcur, perm);
    edge_scatter<<<(e + 255) / 256, 256, 0, stream>>>(srcv, dstv, e, row_ptr, cursor, csr_src);

    const dim3 ggrid(4, (n + 127) / 128);
    const int ablocks = ((n + 3) / 4 + 3) / 4;

    // ---- layer 1 ----
    gemm_mfma<<<ggrid, 256, 0, stream>>>(Xb, n, Wt, bq1, bk1, bv1, bs1, Qp, Kp, Vp, Sp);
    attn<<<ablocks, 256, 0, stream>>>((const uint4*)Qp, (const uint4*)Kp, (const uint4*)Vp,
                                      (const uint4*)Sp, row_ptr, csr_src, perm,
                                      nullptr, (uint4*)Hu, n, 1);

    // ---- layer 2 ----
    gemm_mfma<<<ggrid, 256, 0, stream>>>(Hu, n, Wt + 4 * 16384, bq2, bk2, bv2, bs2, Qp, Kp, Vp, Sp);
    attn<<<ablocks, 256, 0, stream>>>((const uint4*)Qp, (const uint4*)Kp, (const uint4*)Vp,
                                      (const uint4*)Sp, row_ptr, csr_src, perm,
                                      (float*)d_out, nullptr, n, 0);
}

// Round 8
// 338.008 us; speedup vs baseline: 2.0927x; 1.0566x over previous
//
#include <hip/hip_runtime.h>
#include <math.h>

#define D 128

typedef float  f32x4  __attribute__((ext_vector_type(4)));
typedef short  bf16x8 __attribute__((ext_vector_type(8)));

__device__ inline unsigned short bf16r(float f) {
    unsigned u = __float_as_uint(f);
    u = (u + 0x7fff + ((u >> 16) & 1)) >> 16;
    return (unsigned short)u;
}
__device__ inline unsigned bf16pair(float a, float b) {
    return (unsigned)bf16r(a) | ((unsigned)bf16r(b) << 16);
}
__device__ inline float bf16lo(unsigned w) { return __uint_as_float(w << 16); }
__device__ inline float bf16hi(unsigned w) { return __uint_as_float(w & 0xffff0000u); }

__device__ inline void unpack8(uint4 w, float* f) {
    f[0] = bf16lo(w.x); f[1] = bf16hi(w.x);
    f[2] = bf16lo(w.y); f[3] = bf16hi(w.y);
    f[4] = bf16lo(w.z); f[5] = bf16hi(w.z);
    f[6] = bf16lo(w.w); f[7] = bf16hi(w.w);
}

// ---------------------------------------------------------------------------
// prep: fused convert_x + zero(cnt) + convert_w + zero(bh,bcur).
// ---------------------------------------------------------------------------
__global__ __launch_bounds__(256)
void prep(const float* __restrict__ X, unsigned* __restrict__ Xb, int npairs,
          const float* __restrict__ W0, const float* __restrict__ W1,
          const float* __restrict__ W2, const float* __restrict__ W3,
          const float* __restrict__ W4, const float* __restrict__ W5,
          const float* __restrict__ W6, const float* __restrict__ W7,
          unsigned short* __restrict__ Wt,
          int* __restrict__ cnt, int* __restrict__ bh, int* __restrict__ bcur, int n)
{
    const int nxb = (npairs + 255) >> 8;
    const int nz  = (n + 255) >> 8;
    const int b = blockIdx.x;
    if (b < nxb) {
        int i = b * 256 + threadIdx.x;
        if (i < npairs) {
            float2 v = *(const float2*)&X[2 * i];
            Xb[i] = bf16pair(v.x, v.y);
        }
    } else if (b < nxb + nz) {
        int i = (b - nxb) * 256 + threadIdx.x;
        if (i < n) cnt[i] = 0;
    } else if (b < nxb + nz + 8) {
        int wi = b - nxb - nz;
        const float* Ws[8] = {W0, W1, W2, W3, W4, W5, W6, W7};
        const float* W = Ws[wi];
        unsigned short* o = Wt + wi * 16384;
        for (int i = threadIdx.x; i < 16384; i += 256) {
            int k = i >> 7, c = i & 127;
            o[c * 128 + k] = bf16r(W[i]);
        }
    } else {
        if (threadIdx.x < 64) { bh[threadIdx.x] = 0; bcur[threadIdx.x] = 0; }
    }
}

// ---------------------------------------------------------------------------
// MFMA GEMM: A-tile in LDS, B from L2-hot global, coalesced bf16 epilogue.
// ---------------------------------------------------------------------------
__global__ __launch_bounds__(256)
void gemm_mfma(const unsigned short* __restrict__ Xb, int n,
               const unsigned short* __restrict__ Wtall,
               const float* __restrict__ bq, const float* __restrict__ bk,
               const float* __restrict__ bv, const float* __restrict__ bs,
               unsigned short* __restrict__ Qp, unsigned short* __restrict__ Kp,
               unsigned short* __restrict__ Vp, unsigned short* __restrict__ Sp)
{
    const int w = blockIdx.x;
    const int rowBase = blockIdx.y * 128;
    const unsigned short* W = Wtall + w * 16384;
    const float* bias = (w == 0) ? bq : (w == 1) ? bk : (w == 2) ? bv : bs;
    unsigned short* plane = (w == 0) ? Qp : (w == 1) ? Kp : (w == 2) ? Vp : Sp;

    __shared__ unsigned short Asm[128 * 136];

    const int tid  = threadIdx.x;
    const int wave = tid >> 6;
    const int lane = tid & 63;
    const int wr   = wave >> 1;
    const int wc   = wave & 1;
    const int q16  = lane >> 4;
    const int r16  = lane & 15;

    #pragma unroll
    for (int i = 0; i < 8; ++i) {
        int g = tid + 256 * i;
        int m = g >> 4, c = g & 15;
        int row = rowBase + m; if (row >= n) row = n - 1;
        uint4 da = *(const uint4*)(Xb + (size_t)row * 128 + c * 8);
        *(uint4*)&Asm[m * 136 + c * 8] = da;
    }

    const unsigned short* Wbase = W + (size_t)(wc * 64 + r16) * 128 + q16 * 8;
    bf16x8 bcur[4], bnxt[4];
    #pragma unroll
    for (int nj = 0; nj < 4; ++nj)
        bcur[nj] = *(const bf16x8*)(Wbase + nj * 16 * 128);

    __syncthreads();

    f32x4 acc[4][4];
    #pragma unroll
    for (int mi = 0; mi < 4; ++mi)
        #pragma unroll
        for (int nj = 0; nj < 4; ++nj) acc[mi][nj] = (f32x4)(0.f);

    #pragma unroll
    for (int kc = 0; kc < 4; ++kc) {
        if (kc < 3) {
            #pragma unroll
            for (int nj = 0; nj < 4; ++nj)
                bnxt[nj] = *(const bf16x8*)(Wbase + nj * 16 * 128 + (kc + 1) * 32);
        }
        bf16x8 a[4];
        #pragma unroll
        for (int mi = 0; mi < 4; ++mi)
            a[mi] = *(const bf16x8*)&Asm[(wr * 64 + mi * 16 + r16) * 136 + kc * 32 + q16 * 8];
        #pragma unroll
        for (int mi = 0; mi < 4; ++mi)
            #pragma unroll
            for (int nj = 0; nj < 4; ++nj)
                acc[mi][nj] = __builtin_amdgcn_mfma_f32_16x16x32_bf16(a[mi], bcur[nj], acc[mi][nj], 0, 0, 0);
        #pragma unroll
        for (int nj = 0; nj < 4; ++nj) bcur[nj] = bnxt[nj];
    }

    __syncthreads();
    #pragma unroll
    for (int nj = 0; nj < 4; ++nj) {
        const int col = wc * 64 + nj * 16 + r16;
        const float bias_c = bias[col];
        #pragma unroll
        for (int mi = 0; mi < 4; ++mi) {
            const int rbase = wr * 64 + mi * 16 + q16 * 4;
            #pragma unroll
            for (int r = 0; r < 4; ++r)
                Asm[(rbase + r) * 132 + col] = bf16r(acc[mi][nj][r] + bias_c);
        }
    }
    __syncthreads();
    #pragma unroll
    for (int i = 0; i < 8; ++i) {
        int g = tid + 256 * i;
        int m = g >> 4, c = g & 15;
        int row = rowBase + m;
        if (row < n) {
            uint4 d2 = *(const uint4*)&Asm[m * 132 + c * 8];
            *(uint4*)(plane + (size_t)row * 128 + c * 8) = d2;
        }
    }
}

// ---------------------------------------------------------------------------
// CSR build. degree_hist saves each edge's rank (the atomic's return value)
// so edge_scatter needs NO atomics.
// ---------------------------------------------------------------------------
__global__ void degree_hist(const int* __restrict__ dst, int e,
                            int* __restrict__ cnt, int* __restrict__ rank)
{
    int i = blockIdx.x * blockDim.x + threadIdx.x;
    if (i < e) rank[i] = atomicAdd(&cnt[dst[i]], 1);
}

__global__ __launch_bounds__(256)
void scan_hist(const int* __restrict__ cnt, int n, int* __restrict__ bsum, int* __restrict__ bh)
{
    __shared__ int sm[256];
    __shared__ int lh[64];
    if (threadIdx.x < 64) lh[threadIdx.x] = 0;
    int i = blockIdx.x * 256 + threadIdx.x;
    int v = (i < n) ? cnt[i] : 0;
    sm[threadIdx.x] = v;
    __syncthreads();
    if (i < n) atomicAdd(&lh[min(v, 63)], 1);
    #pragma unroll
    for (int off = 128; off > 0; off >>= 1) {
        if (threadIdx.x < off) sm[threadIdx.x] += sm[threadIdx.x + off];
        __syncthreads();
    }
    if (threadIdx.x == 0) bsum[blockIdx.x] = sm[0];
    if (threadIdx.x < 64 && lh[threadIdx.x] > 0)
        atomicAdd(&bh[threadIdx.x], lh[threadIdx.x]);
}

__global__ __launch_bounds__(256)
void scan2(int* __restrict__ bsum, int nb, const int* __restrict__ bh, int* __restrict__ boff)
{
    __shared__ int sm[256];
    int v = (threadIdx.x < nb) ? bsum[threadIdx.x] : 0;
    sm[threadIdx.x] = v;
    __syncthreads();
    int acc = v;
    for (int off = 1; off < 256; off <<= 1) {
        int t = (threadIdx.x >= off) ? sm[threadIdx.x - off] : 0;
        __syncthreads();
        acc += t;
        sm[threadIdx.x] = acc;
        __syncthreads();
    }
    if (threadIdx.x < nb) bsum[threadIdx.x] = acc - v;
    if (threadIdx.x == 0) {
        int run = 0;
        for (int b = 63; b >= 0; --b) { boff[b] = run; run += bh[b]; }
    }
}

__global__ __launch_bounds__(256)
void scan3_scatter(const int* __restrict__ cnt, const int* __restrict__ bsum,
                   int* __restrict__ row_ptr, int n, int e,
                   const int* __restrict__ boff, int* __restrict__ bcur,
                   int* __restrict__ perm)
{
    __shared__ int sm[256];
    __shared__ int lh[64];
    __shared__ int lbase[64];
    if (threadIdx.x < 64) lh[threadIdx.x] = 0;
    __syncthreads();
    int i = blockIdx.x * 256 + threadIdx.x;
    int v = (i < n) ? cnt[i] : 0;
    sm[threadIdx.x] = v;
    int b = 0, local = 0;
    if (i < n) {
        b = min(v, 63);
        local = atomicAdd(&lh[b], 1);
    }
    __syncthreads();
    int acc = v;
    for (int off = 1; off < 256; off <<= 1) {
        int t = (threadIdx.x >= off) ? sm[threadIdx.x - off] : 0;
        __syncthreads();
        acc += t;
        sm[threadIdx.x] = acc;
        __syncthreads();
    }
    if (i < n) row_ptr[i] = bsum[blockIdx.x] + acc - v;
    if (blockIdx.x == 0 && threadIdx.x == 0) row_ptr[n] = e;
    if (threadIdx.x < 64 && lh[threadIdx.x] > 0)
        lbase[threadIdx.x] = atomicAdd(&bcur[threadIdx.x], lh[threadIdx.x]);
    __syncthreads();
    if (i < n) perm[boff[b] + lbase[b] + local] = i;
}

__global__ void edge_scatter(const int* __restrict__ src, const int* __restrict__ dst, int e,
                             const int* __restrict__ row_ptr, const int* __restrict__ rank,
                             int* __restrict__ csr_src)
{
    int i = blockIdx.x * blockDim.x + threadIdx.x;
    if (i < e) {
        int d = dst[i];
        csr_src[row_ptr[d] + rank[i]] = src[i];   // atomic-free
    }
}

// ---------------------------------------------------------------------------
// Attention: 4 nodes per wave (16 lanes/node, 8 ch/lane), degree-sorted perm.
// MAIN LOOP: 4 edges per iteration — 8 gather loads in flight, 4 independent
// dot-reduces, ONE batch-max rescale + 4 exps (serial exp chain cut 4x).
// ---------------------------------------------------------------------------
__global__ __launch_bounds__(256)
void attn(const uint4* __restrict__ Qp, const uint4* __restrict__ Kp,
          const uint4* __restrict__ Vp, const uint4* __restrict__ Sp,
          const int* __restrict__ row_ptr, const int* __restrict__ csr_src,
          const int* __restrict__ perm,
          float* __restrict__ outf, uint4* __restrict__ outb,
          int n, int do_relu)
{
    const int wid  = (blockIdx.x * 256 + threadIdx.x) >> 6;
    const int lane = threadIdx.x & 63;
    const int nq   = lane >> 4;
    const int l16  = lane & 15;
    const int nidx = wid * 4 + nq;
    const int node = (nidx < n) ? perm[nidx] : -1;

    float q[8];
    int beg = 0, end = 0;
    if (node >= 0) {
        uint4 qw = Qp[(size_t)node * 16 + l16];
        unpack8(qw, q);
        beg = row_ptr[node];
        end = row_ptr[node + 1];
    }

    float m = -INFINITY, l = 0.f;
    float acc[8] = {0.f, 0.f, 0.f, 0.f, 0.f, 0.f, 0.f, 0.f};

    int i = beg;
    // ---- 4-edge batched main loop ----
    while (i + 4 <= end) {
        int s0 = csr_src[i], s1 = csr_src[i+1], s2 = csr_src[i+2], s3 = csr_src[i+3];
        uint4 kw0 = Kp[(size_t)s0 * 16 + l16];
        uint4 kw1 = Kp[(size_t)s1 * 16 + l16];
        uint4 kw2 = Kp[(size_t)s2 * 16 + l16];
        uint4 kw3 = Kp[(size_t)s3 * 16 + l16];
        uint4 vw0 = Vp[(size_t)s0 * 16 + l16];
        uint4 vw1 = Vp[(size_t)s1 * 16 + l16];
        uint4 vw2 = Vp[(size_t)s2 * 16 + l16];
        uint4 vw3 = Vp[(size_t)s3 * 16 + l16];

        float kf[8];
        unpack8(kw0, kf);
        float d0 = q[0]*kf[0]+q[1]*kf[1]+q[2]*kf[2]+q[3]*kf[3]+q[4]*kf[4]+q[5]*kf[5]+q[6]*kf[6]+q[7]*kf[7];
        unpack8(kw1, kf);
        float d1 = q[0]*kf[0]+q[1]*kf[1]+q[2]*kf[2]+q[3]*kf[3]+q[4]*kf[4]+q[5]*kf[5]+q[6]*kf[6]+q[7]*kf[7];
        unpack8(kw2, kf);
        float d2 = q[0]*kf[0]+q[1]*kf[1]+q[2]*kf[2]+q[3]*kf[3]+q[4]*kf[4]+q[5]*kf[5]+q[6]*kf[6]+q[7]*kf[7];
        unpack8(kw3, kf);
        float d3 = q[0]*kf[0]+q[1]*kf[1]+q[2]*kf[2]+q[3]*kf[3]+q[4]*kf[4]+q[5]*kf[5]+q[6]*kf[6]+q[7]*kf[7];

        d0 += __shfl_xor(d0, 4, 64); d1 += __shfl_xor(d1, 4, 64);
        d2 += __shfl_xor(d2, 4, 64); d3 += __shfl_xor(d3, 4, 64);
        d0 += __shfl_xor(d0, 2, 64); d1 += __shfl_xor(d1, 2, 64);
        d2 += __shfl_xor(d2, 2, 64); d3 += __shfl_xor(d3, 2, 64);
        d0 += __shfl_xor(d0, 1, 64); d1 += __shfl_xor(d1, 1, 64);
        d2 += __shfl_xor(d2, 1, 64); d3 += __shfl_xor(d3, 1, 64);

        float a0 = d0 * 0.125f, a1 = d1 * 0.125f, a2 = d2 * 0.125f, a3 = d3 * 0.125f;
        float m4 = fmaxf(fmaxf(a0, a1), fmaxf(a2, a3));
        float mn = fmaxf(m, m4);
        float corr = __expf(m - mn);              // exp(-inf)=0 first chunk
        float p0 = __expf(a0 - mn), p1 = __expf(a1 - mn);
        float p2 = __expf(a2 - mn), p3 = __expf(a3 - mn);
        l = l * corr + (p0 + p1 + p2 + p3);

        float v0f[8], v1f[8], v2f[8], v3f[8];
        unpack8(vw0, v0f); unpack8(vw1, v1f); unpack8(vw2, v2f); unpack8(vw3, v3f);
        #pragma unroll
        for (int c2 = 0; c2 < 8; ++c2) {
            float t = acc[c2] * corr;
            t += p0 * v0f[c2]; t += p1 * v1f[c2];
            t += p2 * v2f[c2]; t += p3 * v3f[c2];
            acc[c2] = t;
        }
        m = mn;
        i += 4;
    }
    // ---- tail (<=3 edges) ----
    while (i < end) {
        int s = csr_src[i];
        uint4 kw = Kp[(size_t)s * 16 + l16];
        uint4 vw = Vp[(size_t)s * 16 + l16];
        float kf[8], vf[8];
        unpack8(kw, kf); unpack8(vw, vf);
        float part = q[0]*kf[0]+q[1]*kf[1]+q[2]*kf[2]+q[3]*kf[3]+q[4]*kf[4]+q[5]*kf[5]+q[6]*kf[6]+q[7]*kf[7];
        part += __shfl_xor(part, 4, 64);
        part += __shfl_xor(part, 2, 64);
        part += __shfl_xor(part, 1, 64);
        float alpha = part * 0.125f;
        float mn = fmaxf(m, alpha);
        float corr = __expf(m - mn);
        float p = __expf(alpha - mn);
        l = l * corr + p;
        #pragma unroll
        for (int c2 = 0; c2 < 8; ++c2) acc[c2] = acc[c2] * corr + p * vf[c2];
        m = mn;
        ++i;
    }

    if (node >= 0) {
        float inv = (l > 0.f) ? (1.f / l) : 0.f;
        float sv[8];
        unpack8(Sp[(size_t)node * 16 + l16], sv);
        float r[8];
        #pragma unroll
        for (int c2 = 0; c2 < 8; ++c2) r[c2] = acc[c2] * inv + sv[c2];
        if (do_relu) {
            #pragma unroll
            for (int c2 = 0; c2 < 8; ++c2) r[c2] = fmaxf(r[c2], 0.f);
        }
        if (outb) {
            uint4 o;
            o.x = bf16pair(r[0], r[1]); o.y = bf16pair(r[2], r[3]);
            o.z = bf16pair(r[4], r[5]); o.w = bf16pair(r[6], r[7]);
            outb[(size_t)node * 16 + l16] = o;
        } else {
            *(float4*)&outf[(size_t)node * 128 + l16 * 8]     = make_float4(r[0], r[1], r[2], r[3]);
            *(float4*)&outf[(size_t)node * 128 + l16 * 8 + 4] = make_float4(r[4], r[5], r[6], r[7]);
        }
    }
}

// ---------------------------------------------------------------------------
extern "C" void kernel_launch(void* const* d_in, const int* in_sizes, int n_in,
                              void* d_out, int out_size, void* d_ws, size_t ws_size,
                              hipStream_t stream)
{
    const float* x    = (const float*)d_in[0];
    const int*   edge = (const int*)d_in[1];
    const int n = in_sizes[0] / D;
    const int e = in_sizes[1] / 2;
    const int* srcv = edge;
    const int* dstv = edge + e;

    const float* Wq1 = (const float*)d_in[2];  const float* bq1 = (const float*)d_in[3];
    const float* Wk1 = (const float*)d_in[4];  const float* bk1 = (const float*)d_in[5];
    const float* Wv1 = (const float*)d_in[6];  const float* bv1 = (const float*)d_in[7];
    const float* Ws1 = (const float*)d_in[8];  const float* bs1 = (const float*)d_in[9];
    const float* Wq2 = (const float*)d_in[10]; const float* bq2 = (const float*)d_in[11];
    const float* Wk2 = (const float*)d_in[12]; const float* bk2 = (const float*)d_in[13];
    const float* Wv2 = (const float*)d_in[14]; const float* bv2 = (const float*)d_in[15];
    const float* Ws2 = (const float*)d_in[16]; const float* bs2 = (const float*)d_in[17];

    char* wsb = (char*)d_ws;
    size_t off = 0;
    auto alloc = [&](size_t bytes) -> void* {
        void* p = wsb + off;
        off += (bytes + 255) & ~(size_t)255;
        return p;
    };
    unsigned short* Qp = (unsigned short*)alloc((size_t)n * D * sizeof(unsigned short));
    unsigned short* Kp = (unsigned short*)alloc((size_t)n * D * sizeof(unsigned short));
    unsigned short* Vp = (unsigned short*)alloc((size_t)n * D * sizeof(unsigned short));
    unsigned short* Sp = (unsigned short*)alloc((size_t)n * D * sizeof(unsigned short));
    unsigned short* Xb = (unsigned short*)alloc((size_t)n * D * sizeof(unsigned short));
    unsigned short* Hu = (unsigned short*)alloc((size_t)n * D * sizeof(unsigned short));
    unsigned short* Wt = (unsigned short*)alloc(8 * 16384 * sizeof(unsigned short));
    int* cnt     = (int*)alloc((size_t)n * sizeof(int));
    int* row_ptr = (int*)alloc((size_t)(n + 1) * sizeof(int));
    int* bsum    = (int*)alloc(1024 * sizeof(int));
    int* perm    = (int*)alloc((size_t)n * sizeof(int));
    int* bh      = (int*)alloc(64 * sizeof(int));
    int* bcur    = (int*)alloc(64 * sizeof(int));
    int* boff    = (int*)alloc(64 * sizeof(int));
    int* rank    = (int*)alloc((size_t)e * sizeof(int));
    int* csr_src = (int*)alloc((size_t)e * sizeof(int));
    (void)ws_size; (void)n_in; (void)out_size;

    const int nb  = (n + 255) / 256;
    const int npairs = n * 64;
    const int nprep  = (npairs + 255) / 256 + nb + 8 + 1;

    prep<<<nprep, 256, 0, stream>>>(x, (unsigned*)Xb, npairs,
        Wq1, Wk1, Wv1, Ws1, Wq2, Wk2, Wv2, Ws2, Wt, cnt, bh, bcur, n);

    degree_hist<<<(e + 255) / 256, 256, 0, stream>>>(dstv, e, cnt, rank);
    scan_hist<<<nb, 256, 0, stream>>>(cnt, n, bsum, bh);
    scan2<<<1, 256, 0, stream>>>(bsum, nb, bh, boff);
    scan3_scatter<<<nb, 256, 0, stream>>>(cnt, bsum, row_ptr, n, e, boff, bcur, perm);
    edge_scatter<<<(e + 255) / 256, 256, 0, stream>>>(srcv, dstv, e, row_ptr, rank, csr_src);

    const dim3 ggrid(4, (n + 127) / 128);
    const int ablocks = ((n + 3) / 4 + 3) / 4;

    // ---- layer 1 ----
    gemm_mfma<<<ggrid, 256, 0, stream>>>(Xb, n, Wt, bq1, bk1, bv1, bs1, Qp, Kp, Vp, Sp);
    attn<<<ablocks, 256, 0, stream>>>((const uint4*)Qp, (const uint4*)Kp, (const uint4*)Vp,
                                      (const uint4*)Sp, row_ptr, csr_src, perm,
                                      nullptr, (uint4*)Hu, n, 1);

    // ---- layer 2 ----
    gemm_mfma<<<ggrid, 256, 0, stream>>>(Hu, n, Wt + 4 * 16384, bq2, bk2, bv2, bs2, Qp, Kp, Vp, Sp);
    attn<<<ablocks, 256, 0, stream>>>((const uint4*)Qp, (const uint4*)Kp, (const uint4*)Vp,
                                      (const uint4*)Sp, row_ptr, csr_src, perm,
                                      (float*)d_out, nullptr, n, 0);
}

// Round 9
// 335.107 us; speedup vs baseline: 2.1108x; 1.0087x over previous
//
#include <hip/hip_runtime.h>
#include <math.h>

#define D 128

typedef float  f32x4  __attribute__((ext_vector_type(4)));
typedef short  bf16x8 __attribute__((ext_vector_type(8)));

__device__ inline unsigned short bf16r(float f) {
    unsigned u = __float_as_uint(f);
    u = (u + 0x7fff + ((u >> 16) & 1)) >> 16;
    return (unsigned short)u;
}
__device__ inline unsigned bf16pair(float a, float b) {
    return (unsigned)bf16r(a) | ((unsigned)bf16r(b) << 16);
}
__device__ inline float bf16lo(unsigned w) { return __uint_as_float(w << 16); }
__device__ inline float bf16hi(unsigned w) { return __uint_as_float(w & 0xffff0000u); }

__device__ inline void unpack8(uint4 w, float* f) {
    f[0] = bf16lo(w.x); f[1] = bf16hi(w.x);
    f[2] = bf16lo(w.y); f[3] = bf16hi(w.y);
    f[4] = bf16lo(w.z); f[5] = bf16hi(w.z);
    f[6] = bf16lo(w.w); f[7] = bf16hi(w.w);
}

// ---------------------------------------------------------------------------
// prep: fused convert_x + zero(cnt) + convert_w + zero(bh,bcur).
// ---------------------------------------------------------------------------
__global__ __launch_bounds__(256)
void prep(const float* __restrict__ X, unsigned* __restrict__ Xb, int npairs,
          const float* __restrict__ W0, const float* __restrict__ W1,
          const float* __restrict__ W2, const float* __restrict__ W3,
          const float* __restrict__ W4, const float* __restrict__ W5,
          const float* __restrict__ W6, const float* __restrict__ W7,
          unsigned short* __restrict__ Wt,
          int* __restrict__ cnt, int* __restrict__ bh, int* __restrict__ bcur, int n)
{
    const int nxb = (npairs + 255) >> 8;
    const int nz  = (n + 255) >> 8;
    const int b = blockIdx.x;
    if (b < nxb) {
        int i = b * 256 + threadIdx.x;
        if (i < npairs) {
            float2 v = *(const float2*)&X[2 * i];
            Xb[i] = bf16pair(v.x, v.y);
        }
    } else if (b < nxb + nz) {
        int i = (b - nxb) * 256 + threadIdx.x;
        if (i < n) cnt[i] = 0;
    } else if (b < nxb + nz + 8) {
        int wi = b - nxb - nz;
        const float* Ws[8] = {W0, W1, W2, W3, W4, W5, W6, W7};
        const float* W = Ws[wi];
        unsigned short* o = Wt + wi * 16384;
        for (int i = threadIdx.x; i < 16384; i += 256) {
            int k = i >> 7, c = i & 127;
            o[c * 128 + k] = bf16r(W[i]);
        }
    } else {
        if (threadIdx.x < 64) { bh[threadIdx.x] = 0; bcur[threadIdx.x] = 0; }
    }
}

// ---------------------------------------------------------------------------
// MFMA GEMM: A-tile in LDS, B from L2-hot global, coalesced bf16 epilogue.
// K and V interleave into one KV plane: node row = 256 bf16 (K: 0..127, V: 128..255).
// ---------------------------------------------------------------------------
__global__ __launch_bounds__(256)
void gemm_mfma(const unsigned short* __restrict__ Xb, int n,
               const unsigned short* __restrict__ Wtall,
               const float* __restrict__ bq, const float* __restrict__ bk,
               const float* __restrict__ bv, const float* __restrict__ bs,
               unsigned short* __restrict__ Qp, unsigned short* __restrict__ KVp,
               unsigned short* __restrict__ Sp)
{
    const int w = blockIdx.x;
    const int rowBase = blockIdx.y * 128;
    const unsigned short* W = Wtall + w * 16384;
    const float* bias = (w == 0) ? bq : (w == 1) ? bk : (w == 2) ? bv : bs;
    unsigned short* base; int rstride, coff;
    if (w == 0)      { base = Qp;  rstride = 128; coff = 0; }
    else if (w == 1) { base = KVp; rstride = 256; coff = 0; }
    else if (w == 2) { base = KVp; rstride = 256; coff = 128; }
    else             { base = Sp;  rstride = 128; coff = 0; }

    __shared__ unsigned short Asm[128 * 136];

    const int tid  = threadIdx.x;
    const int wave = tid >> 6;
    const int lane = tid & 63;
    const int wr   = wave >> 1;
    const int wc   = wave & 1;
    const int q16  = lane >> 4;
    const int r16  = lane & 15;

    #pragma unroll
    for (int i = 0; i < 8; ++i) {
        int g = tid + 256 * i;
        int m = g >> 4, c = g & 15;
        int row = rowBase + m; if (row >= n) row = n - 1;
        uint4 da = *(const uint4*)(Xb + (size_t)row * 128 + c * 8);
        *(uint4*)&Asm[m * 136 + c * 8] = da;
    }

    const unsigned short* Wbase = W + (size_t)(wc * 64 + r16) * 128 + q16 * 8;
    bf16x8 bcur[4], bnxt[4];
    #pragma unroll
    for (int nj = 0; nj < 4; ++nj)
        bcur[nj] = *(const bf16x8*)(Wbase + nj * 16 * 128);

    __syncthreads();

    f32x4 acc[4][4];
    #pragma unroll
    for (int mi = 0; mi < 4; ++mi)
        #pragma unroll
        for (int nj = 0; nj < 4; ++nj) acc[mi][nj] = (f32x4)(0.f);

    #pragma unroll
    for (int kc = 0; kc < 4; ++kc) {
        if (kc < 3) {
            #pragma unroll
            for (int nj = 0; nj < 4; ++nj)
                bnxt[nj] = *(const bf16x8*)(Wbase + nj * 16 * 128 + (kc + 1) * 32);
        }
        bf16x8 a[4];
        #pragma unroll
        for (int mi = 0; mi < 4; ++mi)
            a[mi] = *(const bf16x8*)&Asm[(wr * 64 + mi * 16 + r16) * 136 + kc * 32 + q16 * 8];
        #pragma unroll
        for (int mi = 0; mi < 4; ++mi)
            #pragma unroll
            for (int nj = 0; nj < 4; ++nj)
                acc[mi][nj] = __builtin_amdgcn_mfma_f32_16x16x32_bf16(a[mi], bcur[nj], acc[mi][nj], 0, 0, 0);
        #pragma unroll
        for (int nj = 0; nj < 4; ++nj) bcur[nj] = bnxt[nj];
    }

    __syncthreads();
    #pragma unroll
    for (int nj = 0; nj < 4; ++nj) {
        const int col = wc * 64 + nj * 16 + r16;
        const float bias_c = bias[col];
        #pragma unroll
        for (int mi = 0; mi < 4; ++mi) {
            const int rbase = wr * 64 + mi * 16 + q16 * 4;
            #pragma unroll
            for (int r = 0; r < 4; ++r)
                Asm[(rbase + r) * 132 + col] = bf16r(acc[mi][nj][r] + bias_c);
        }
    }
    __syncthreads();
    #pragma unroll
    for (int i = 0; i < 8; ++i) {
        int g = tid + 256 * i;
        int m = g >> 4, c = g & 15;
        int row = rowBase + m;
        if (row < n) {
            uint4 d2 = *(const uint4*)&Asm[m * 132 + c * 8];
            *(uint4*)(base + (size_t)row * rstride + coff + c * 8) = d2;
        }
    }
}

// ---------------------------------------------------------------------------
// CSR build. degree_hist saves each edge's rank; edge_scatter is atomic-free.
// ---------------------------------------------------------------------------
__global__ void degree_hist(const int* __restrict__ dst, int e,
                            int* __restrict__ cnt, int* __restrict__ rank)
{
    int i = blockIdx.x * blockDim.x + threadIdx.x;
    if (i < e) rank[i] = atomicAdd(&cnt[dst[i]], 1);
}

__global__ __launch_bounds__(256)
void scan_hist(const int* __restrict__ cnt, int n, int* __restrict__ bsum, int* __restrict__ bh)
{
    __shared__ int sm[256];
    __shared__ int lh[64];
    if (threadIdx.x < 64) lh[threadIdx.x] = 0;
    int i = blockIdx.x * 256 + threadIdx.x;
    int v = (i < n) ? cnt[i] : 0;
    sm[threadIdx.x] = v;
    __syncthreads();
    if (i < n) atomicAdd(&lh[min(v, 63)], 1);
    #pragma unroll
    for (int off = 128; off > 0; off >>= 1) {
        if (threadIdx.x < off) sm[threadIdx.x] += sm[threadIdx.x + off];
        __syncthreads();
    }
    if (threadIdx.x == 0) bsum[blockIdx.x] = sm[0];
    if (threadIdx.x < 64 && lh[threadIdx.x] > 0)
        atomicAdd(&bh[threadIdx.x], lh[threadIdx.x]);
}

__global__ __launch_bounds__(256)
void scan2(int* __restrict__ bsum, int nb, const int* __restrict__ bh, int* __restrict__ boff)
{
    __shared__ int sm[256];
    int v = (threadIdx.x < nb) ? bsum[threadIdx.x] : 0;
    sm[threadIdx.x] = v;
    __syncthreads();
    int acc = v;
    for (int off = 1; off < 256; off <<= 1) {
        int t = (threadIdx.x >= off) ? sm[threadIdx.x - off] : 0;
        __syncthreads();
        acc += t;
        sm[threadIdx.x] = acc;
        __syncthreads();
    }
    if (threadIdx.x < nb) bsum[threadIdx.x] = acc - v;
    if (threadIdx.x == 0) {
        int run = 0;
        for (int b = 63; b >= 0; --b) { boff[b] = run; run += bh[b]; }
    }
}

__global__ __launch_bounds__(256)
void scan3_scatter(const int* __restrict__ cnt, const int* __restrict__ bsum,
                   int* __restrict__ row_ptr, int n, int e,
                   const int* __restrict__ boff, int* __restrict__ bcur,
                   int* __restrict__ perm)
{
    __shared__ int sm[256];
    __shared__ int lh[64];
    __shared__ int lbase[64];
    if (threadIdx.x < 64) lh[threadIdx.x] = 0;
    __syncthreads();
    int i = blockIdx.x * 256 + threadIdx.x;
    int v = (i < n) ? cnt[i] : 0;
    sm[threadIdx.x] = v;
    int b = 0, local = 0;
    if (i < n) {
        b = min(v, 63);
        local = atomicAdd(&lh[b], 1);
    }
    __syncthreads();
    int acc = v;
    for (int off = 1; off < 256; off <<= 1) {
        int t = (threadIdx.x >= off) ? sm[threadIdx.x - off] : 0;
        __syncthreads();
        acc += t;
        sm[threadIdx.x] = acc;
        __syncthreads();
    }
    if (i < n) row_ptr[i] = bsum[blockIdx.x] + acc - v;
    if (blockIdx.x == 0 && threadIdx.x == 0) row_ptr[n] = e;
    if (threadIdx.x < 64 && lh[threadIdx.x] > 0)
        lbase[threadIdx.x] = atomicAdd(&bcur[threadIdx.x], lh[threadIdx.x]);
    __syncthreads();
    if (i < n) perm[boff[b] + lbase[b] + local] = i;
}

__global__ void edge_scatter(const int* __restrict__ src, const int* __restrict__ dst, int e,
                             const int* __restrict__ row_ptr, const int* __restrict__ rank,
                             int* __restrict__ csr_src)
{
    int i = blockIdx.x * blockDim.x + threadIdx.x;
    if (i < e) {
        int d = dst[i];
        csr_src[row_ptr[d] + rank[i]] = src[i];
    }
}

// ---------------------------------------------------------------------------
// Attention helpers: 4-edge chunk load / consume (16 lanes per node).
// ---------------------------------------------------------------------------
__device__ inline void load4(const uint4* __restrict__ KV, const int* __restrict__ csr,
                             int i, int l16, uint4* k, uint4* v)
{
    int s0 = csr[i], s1 = csr[i+1], s2 = csr[i+2], s3 = csr[i+3];
    k[0] = KV[(size_t)s0 * 32 + l16];      v[0] = KV[(size_t)s0 * 32 + 16 + l16];
    k[1] = KV[(size_t)s1 * 32 + l16];      v[1] = KV[(size_t)s1 * 32 + 16 + l16];
    k[2] = KV[(size_t)s2 * 32 + l16];      v[2] = KV[(size_t)s2 * 32 + 16 + l16];
    k[3] = KV[(size_t)s3 * 32 + l16];      v[3] = KV[(size_t)s3 * 32 + 16 + l16];
}

__device__ inline void consume4(const uint4* k, const uint4* v, const float* q,
                                float& m, float& l, float* acc)
{
    float kf[8];
    unpack8(k[0], kf);
    float d0 = q[0]*kf[0]+q[1]*kf[1]+q[2]*kf[2]+q[3]*kf[3]+q[4]*kf[4]+q[5]*kf[5]+q[6]*kf[6]+q[7]*kf[7];
    unpack8(k[1], kf);
    float d1 = q[0]*kf[0]+q[1]*kf[1]+q[2]*kf[2]+q[3]*kf[3]+q[4]*kf[4]+q[5]*kf[5]+q[6]*kf[6]+q[7]*kf[7];
    unpack8(k[2], kf);
    float d2 = q[0]*kf[0]+q[1]*kf[1]+q[2]*kf[2]+q[3]*kf[3]+q[4]*kf[4]+q[5]*kf[5]+q[6]*kf[6]+q[7]*kf[7];
    unpack8(k[3], kf);
    float d3 = q[0]*kf[0]+q[1]*kf[1]+q[2]*kf[2]+q[3]*kf[3]+q[4]*kf[4]+q[5]*kf[5]+q[6]*kf[6]+q[7]*kf[7];

    d0 += __shfl_xor(d0, 4, 64); d1 += __shfl_xor(d1, 4, 64);
    d2 += __shfl_xor(d2, 4, 64); d3 += __shfl_xor(d3, 4, 64);
    d0 += __shfl_xor(d0, 2, 64); d1 += __shfl_xor(d1, 2, 64);
    d2 += __shfl_xor(d2, 2, 64); d3 += __shfl_xor(d3, 2, 64);
    d0 += __shfl_xor(d0, 1, 64); d1 += __shfl_xor(d1, 1, 64);
    d2 += __shfl_xor(d2, 1, 64); d3 += __shfl_xor(d3, 1, 64);

    float a0 = d0 * 0.125f, a1 = d1 * 0.125f, a2 = d2 * 0.125f, a3 = d3 * 0.125f;
    float m4 = fmaxf(fmaxf(a0, a1), fmaxf(a2, a3));
    float mn = fmaxf(m, m4);
    float corr = __expf(m - mn);
    float p0 = __expf(a0 - mn), p1 = __expf(a1 - mn);
    float p2 = __expf(a2 - mn), p3 = __expf(a3 - mn);
    l = l * corr + (p0 + p1 + p2 + p3);

    float v0f[8], v1f[8], v2f[8], v3f[8];
    unpack8(v[0], v0f); unpack8(v[1], v1f); unpack8(v[2], v2f); unpack8(v[3], v3f);
    #pragma unroll
    for (int c2 = 0; c2 < 8; ++c2) {
        float t = acc[c2] * corr;
        t += p0 * v0f[c2]; t += p1 * v1f[c2];
        t += p2 * v2f[c2]; t += p3 * v3f[c2];
        acc[c2] = t;
    }
    m = mn;
}

// ---------------------------------------------------------------------------
// Attention: 4 nodes/wave, 4-edge chunks, software-pipelined double buffer
// (load chunk B while consuming chunk A, ping-pong; <=1 register copy).
// ---------------------------------------------------------------------------
__global__ __launch_bounds__(256)
void attn(const uint4* __restrict__ Qp, const uint4* __restrict__ KV,
          const uint4* __restrict__ Sp,
          const int* __restrict__ row_ptr, const int* __restrict__ csr_src,
          const int* __restrict__ perm,
          float* __restrict__ outf, uint4* __restrict__ outb,
          int n, int do_relu)
{
    const int wid  = (blockIdx.x * 256 + threadIdx.x) >> 6;
    const int lane = threadIdx.x & 63;
    const int nq   = lane >> 4;
    const int l16  = lane & 15;
    const int nidx = wid * 4 + nq;
    const int node = (nidx < n) ? perm[nidx] : -1;

    float q[8];
    int beg = 0, end = 0;
    if (node >= 0) {
        uint4 qw = Qp[(size_t)node * 16 + l16];
        unpack8(qw, q);
        beg = row_ptr[node];
        end = row_ptr[node + 1];
    }

    float m = -INFINITY, l = 0.f;
    float acc[8] = {0.f, 0.f, 0.f, 0.f, 0.f, 0.f, 0.f, 0.f};

    int i = beg;
    uint4 ka[4], va[4], kb[4], vb[4];
    if (i + 4 <= end) load4(KV, csr_src, i, l16, ka, va);
    while (i + 8 <= end) {
        load4(KV, csr_src, i + 4, l16, kb, vb);
        consume4(ka, va, q, m, l, acc);
        i += 4;
        if (i + 8 <= end) {
            load4(KV, csr_src, i + 4, l16, ka, va);
            consume4(kb, vb, q, m, l, acc);
            i += 4;
        } else {
            #pragma unroll
            for (int t = 0; t < 4; ++t) { ka[t] = kb[t]; va[t] = vb[t]; }
        }
    }
    if (i + 4 <= end) {
        consume4(ka, va, q, m, l, acc);
        i += 4;
    }
    // tail (<=3 edges)
    while (i < end) {
        int s = csr_src[i];
        uint4 kw = KV[(size_t)s * 32 + l16];
        uint4 vw = KV[(size_t)s * 32 + 16 + l16];
        float kf[8], vf[8];
        unpack8(kw, kf); unpack8(vw, vf);
        float part = q[0]*kf[0]+q[1]*kf[1]+q[2]*kf[2]+q[3]*kf[3]+q[4]*kf[4]+q[5]*kf[5]+q[6]*kf[6]+q[7]*kf[7];
        part += __shfl_xor(part, 4, 64);
        part += __shfl_xor(part, 2, 64);
        part += __shfl_xor(part, 1, 64);
        float alpha = part * 0.125f;
        float mn = fmaxf(m, alpha);
        float corr = __expf(m - mn);
        float p = __expf(alpha - mn);
        l = l * corr + p;
        #pragma unroll
        for (int c2 = 0; c2 < 8; ++c2) acc[c2] = acc[c2] * corr + p * vf[c2];
        m = mn;
        ++i;
    }

    if (node >= 0) {
        float inv = (l > 0.f) ? (1.f / l) : 0.f;
        float sv[8];
        unpack8(Sp[(size_t)node * 16 + l16], sv);
        float r[8];
        #pragma unroll
        for (int c2 = 0; c2 < 8; ++c2) r[c2] = acc[c2] * inv + sv[c2];
        if (do_relu) {
            #pragma unroll
            for (int c2 = 0; c2 < 8; ++c2) r[c2] = fmaxf(r[c2], 0.f);
        }
        if (outb) {
            uint4 o;
            o.x = bf16pair(r[0], r[1]); o.y = bf16pair(r[2], r[3]);
            o.z = bf16pair(r[4], r[5]); o.w = bf16pair(r[6], r[7]);
            outb[(size_t)node * 16 + l16] = o;
        } else {
            *(float4*)&outf[(size_t)node * 128 + l16 * 8]     = make_float4(r[0], r[1], r[2], r[3]);
            *(float4*)&outf[(size_t)node * 128 + l16 * 8 + 4] = make_float4(r[4], r[5], r[6], r[7]);
        }
    }
}

// ---------------------------------------------------------------------------
extern "C" void kernel_launch(void* const* d_in, const int* in_sizes, int n_in,
                              void* d_out, int out_size, void* d_ws, size_t ws_size,
                              hipStream_t stream)
{
    const float* x    = (const float*)d_in[0];
    const int*   edge = (const int*)d_in[1];
    const int n = in_sizes[0] / D;
    const int e = in_sizes[1] / 2;
    const int* srcv = edge;
    const int* dstv = edge + e;

    const float* Wq1 = (const float*)d_in[2];  const float* bq1 = (const float*)d_in[3];
    const float* Wk1 = (const float*)d_in[4];  const float* bk1 = (const float*)d_in[5];
    const float* Wv1 = (const float*)d_in[6];  const float* bv1 = (const float*)d_in[7];
    const float* Ws1 = (const float*)d_in[8];  const float* bs1 = (const float*)d_in[9];
    const float* Wq2 = (const float*)d_in[10]; const float* bq2 = (const float*)d_in[11];
    const float* Wk2 = (const float*)d_in[12]; const float* bk2 = (const float*)d_in[13];
    const float* Wv2 = (const float*)d_in[14]; const float* bv2 = (const float*)d_in[15];
    const float* Ws2 = (const float*)d_in[16]; const float* bs2 = (const float*)d_in[17];

    char* wsb = (char*)d_ws;
    size_t off = 0;
    auto alloc = [&](size_t bytes) -> void* {
        void* p = wsb + off;
        off += (bytes + 255) & ~(size_t)255;
        return p;
    };
    unsigned short* Qp  = (unsigned short*)alloc((size_t)n * D * sizeof(unsigned short));
    unsigned short* KVp = (unsigned short*)alloc((size_t)n * 2 * D * sizeof(unsigned short));
    unsigned short* Sp  = (unsigned short*)alloc((size_t)n * D * sizeof(unsigned short));
    unsigned short* Xb  = (unsigned short*)alloc((size_t)n * D * sizeof(unsigned short));
    unsigned short* Hu  = (unsigned short*)alloc((size_t)n * D * sizeof(unsigned short));
    unsigned short* Wt  = (unsigned short*)alloc(8 * 16384 * sizeof(unsigned short));
    int* cnt     = (int*)alloc((size_t)n * sizeof(int));
    int* row_ptr = (int*)alloc((size_t)(n + 1) * sizeof(int));
    int* bsum    = (int*)alloc(1024 * sizeof(int));
    int* perm    = (int*)alloc((size_t)n * sizeof(int));
    int* bh      = (int*)alloc(64 * sizeof(int));
    int* bcur    = (int*)alloc(64 * sizeof(int));
    int* boff    = (int*)alloc(64 * sizeof(int));
    int* rank    = (int*)alloc((size_t)e * sizeof(int));
    int* csr_src = (int*)alloc((size_t)e * sizeof(int));
    (void)ws_size; (void)n_in; (void)out_size;

    const int nb  = (n + 255) / 256;
    const int npairs = n * 64;
    const int nprep  = (npairs + 255) / 256 + nb + 8 + 1;

    prep<<<nprep, 256, 0, stream>>>(x, (unsigned*)Xb, npairs,
        Wq1, Wk1, Wv1, Ws1, Wq2, Wk2, Wv2, Ws2, Wt, cnt, bh, bcur, n);

    degree_hist<<<(e + 255) / 256, 256, 0, stream>>>(dstv, e, cnt, rank);
    scan_hist<<<nb, 256, 0, stream>>>(cnt, n, bsum, bh);
    scan2<<<1, 256, 0, stream>>>(bsum, nb, bh, boff);
    scan3_scatter<<<nb, 256, 0, stream>>>(cnt, bsum, row_ptr, n, e, boff, bcur, perm);
    edge_scatter<<<(e + 255) / 256, 256, 0, stream>>>(srcv, dstv, e, row_ptr, rank, csr_src);

    const dim3 ggrid(4, (n + 127) / 128);
    const int ablocks = ((n + 3) / 4 + 3) / 4;

    // ---- layer 1 ----
    gemm_mfma<<<ggrid, 256, 0, stream>>>(Xb, n, Wt, bq1, bk1, bv1, bs1, Qp, KVp, Sp);
    attn<<<ablocks, 256, 0, stream>>>((const uint4*)Qp, (const uint4*)KVp, (const uint4*)Sp,
                                      row_ptr, csr_src, perm, nullptr, (uint4*)Hu, n, 1);

    // ---- layer 2 ----
    gemm_mfma<<<ggrid, 256, 0, stream>>>(Hu, n, Wt + 4 * 16384, bq2, bk2, bv2, bs2, Qp, KVp, Sp);
    attn<<<ablocks, 256, 0, stream>>>((const uint4*)Qp, (const uint4*)KVp, (const uint4*)Sp,
                                      row_ptr, csr_src, perm, (float*)d_out, nullptr, n, 0);
}

// Round 10
// 314.864 us; speedup vs baseline: 2.2465x; 1.0643x over previous
//
#include <hip/hip_runtime.h>
#include <math.h>

#define D 128

typedef float  f32x4  __attribute__((ext_vector_type(4)));
typedef float  f32x2  __attribute__((ext_vector_type(2)));
typedef short  bf16x8 __attribute__((ext_vector_type(8)));

__device__ inline unsigned short bf16r(float f) {
    unsigned u = __float_as_uint(f);
    u = (u + 0x7fff + ((u >> 16) & 1)) >> 16;
    return (unsigned short)u;
}
__device__ inline unsigned bf16pair(float a, float b) {
    return (unsigned)bf16r(a) | ((unsigned)bf16r(b) << 16);
}
__device__ inline float bf16lo(unsigned w) { return __uint_as_float(w << 16); }
__device__ inline float bf16hi(unsigned w) { return __uint_as_float(w & 0xffff0000u); }

__device__ inline void unpack8(uint4 w, float* f) {
    f[0] = bf16lo(w.x); f[1] = bf16hi(w.x);
    f[2] = bf16lo(w.y); f[3] = bf16hi(w.y);
    f[4] = bf16lo(w.z); f[5] = bf16hi(w.z);
    f[6] = bf16lo(w.w); f[7] = bf16hi(w.w);
}

// 4 floats -> 4 fp8 e4m3 packed in one dword (HW RNE)
__device__ inline unsigned pk_fp8x4(float a, float b, float c, float d) {
    unsigned w = 0;
    w = __builtin_amdgcn_cvt_pk_fp8_f32(a, b, w, false);
    w = __builtin_amdgcn_cvt_pk_fp8_f32(c, d, w, true);
    return w;
}

// dot of q[0..7] with 8 fp8 channels held in a uint2
__device__ inline float dot8_fp8(const float* q, uint2 kw) {
    f32x2 p;
    p = __builtin_amdgcn_cvt_pk_f32_fp8((int)kw.x, false);
    float s = q[0] * p.x + q[1] * p.y;
    p = __builtin_amdgcn_cvt_pk_f32_fp8((int)kw.x, true);
    s += q[2] * p.x + q[3] * p.y;
    p = __builtin_amdgcn_cvt_pk_f32_fp8((int)kw.y, false);
    s += q[4] * p.x + q[5] * p.y;
    p = __builtin_amdgcn_cvt_pk_f32_fp8((int)kw.y, true);
    s += q[6] * p.x + q[7] * p.y;
    return s;
}

// ---------------------------------------------------------------------------
// prep: fused convert_x + zero(cnt) + convert_w + zero(bh,bcur).
// ---------------------------------------------------------------------------
__global__ __launch_bounds__(256)
void prep(const float* __restrict__ X, unsigned* __restrict__ Xb, int npairs,
          const float* __restrict__ W0, const float* __restrict__ W1,
          const float* __restrict__ W2, const float* __restrict__ W3,
          const float* __restrict__ W4, const float* __restrict__ W5,
          const float* __restrict__ W6, const float* __restrict__ W7,
          unsigned short* __restrict__ Wt,
          int* __restrict__ cnt, int* __restrict__ bh, int* __restrict__ bcur, int n)
{
    const int nxb = (npairs + 255) >> 8;
    const int nz  = (n + 255) >> 8;
    const int b = blockIdx.x;
    if (b < nxb) {
        int i = b * 256 + threadIdx.x;
        if (i < npairs) {
            float2 v = *(const float2*)&X[2 * i];
            Xb[i] = bf16pair(v.x, v.y);
        }
    } else if (b < nxb + nz) {
        int i = (b - nxb) * 256 + threadIdx.x;
        if (i < n) cnt[i] = 0;
    } else if (b < nxb + nz + 8) {
        int wi = b - nxb - nz;
        const float* Ws[8] = {W0, W1, W2, W3, W4, W5, W6, W7};
        const float* W = Ws[wi];
        unsigned short* o = Wt + wi * 16384;
        for (int i = threadIdx.x; i < 16384; i += 256) {
            int k = i >> 7, c = i & 127;
            o[c * 128 + k] = bf16r(W[i]);
        }
    } else {
        if (threadIdx.x < 64) { bh[threadIdx.x] = 0; bcur[threadIdx.x] = 0; }
    }
}

// ---------------------------------------------------------------------------
// Fused MFMA GEMM + (optional) edge_scatter tail blocks.
// gemm: A-tile in LDS, B from L2-hot global, coalesced epilogue.
// Outputs: Q,V,S bf16 planes; K as fp8 e4m3 plane (128B/row).
// es blocks (bid >= gemmBlocks) exit before any barrier — legal divergence.
// ---------------------------------------------------------------------------
__global__ __launch_bounds__(256)
void gemm_es(const unsigned short* __restrict__ Xb, int n,
             const unsigned short* __restrict__ Wtall,
             const float* __restrict__ bq, const float* __restrict__ bk,
             const float* __restrict__ bv, const float* __restrict__ bs,
             unsigned short* __restrict__ Qp, unsigned char* __restrict__ K8,
             unsigned short* __restrict__ Vp, unsigned short* __restrict__ Sp,
             int gemmBlocks,
             const int* __restrict__ src, const int* __restrict__ dst, int e,
             const int* __restrict__ row_ptr, const int* __restrict__ rank,
             int* __restrict__ csr_src)
{
    const int bid = blockIdx.x;
    if (bid >= gemmBlocks) {           // -------- edge_scatter part --------
        int i = (bid - gemmBlocks) * 256 + threadIdx.x;
        if (i < e) {
            int d = dst[i];
            csr_src[row_ptr[d] + rank[i]] = src[i];   // atomic-free
        }
        return;
    }
    // ----------------------------- gemm part ------------------------------
    const int w = bid & 3;
    const int rowBase = (bid >> 2) * 128;
    const unsigned short* W = Wtall + w * 16384;
    const float* bias = (w == 0) ? bq : (w == 1) ? bk : (w == 2) ? bv : bs;

    __shared__ unsigned short Asm[128 * 136];

    const int tid  = threadIdx.x;
    const int wave = tid >> 6;
    const int lane = tid & 63;
    const int wr   = wave >> 1;
    const int wc   = wave & 1;
    const int q16  = lane >> 4;
    const int r16  = lane & 15;

    #pragma unroll
    for (int i = 0; i < 8; ++i) {
        int g = tid + 256 * i;
        int m = g >> 4, c = g & 15;
        int row = rowBase + m; if (row >= n) row = n - 1;
        uint4 da = *(const uint4*)(Xb + (size_t)row * 128 + c * 8);
        *(uint4*)&Asm[m * 136 + c * 8] = da;
    }

    const unsigned short* Wbase = W + (size_t)(wc * 64 + r16) * 128 + q16 * 8;
    bf16x8 bcu[4], bnx[4];
    #pragma unroll
    for (int nj = 0; nj < 4; ++nj)
        bcu[nj] = *(const bf16x8*)(Wbase + nj * 16 * 128);

    __syncthreads();

    f32x4 acc[4][4];
    #pragma unroll
    for (int mi = 0; mi < 4; ++mi)
        #pragma unroll
        for (int nj = 0; nj < 4; ++nj) acc[mi][nj] = (f32x4)(0.f);

    #pragma unroll
    for (int kc = 0; kc < 4; ++kc) {
        if (kc < 3) {
            #pragma unroll
            for (int nj = 0; nj < 4; ++nj)
                bnx[nj] = *(const bf16x8*)(Wbase + nj * 16 * 128 + (kc + 1) * 32);
        }
        bf16x8 a[4];
        #pragma unroll
        for (int mi = 0; mi < 4; ++mi)
            a[mi] = *(const bf16x8*)&Asm[(wr * 64 + mi * 16 + r16) * 136 + kc * 32 + q16 * 8];
        #pragma unroll
        for (int mi = 0; mi < 4; ++mi)
            #pragma unroll
            for (int nj = 0; nj < 4; ++nj)
                acc[mi][nj] = __builtin_amdgcn_mfma_f32_16x16x32_bf16(a[mi], bcu[nj], acc[mi][nj], 0, 0, 0);
        #pragma unroll
        for (int nj = 0; nj < 4; ++nj) bcu[nj] = bnx[nj];
    }

    __syncthreads();
    #pragma unroll
    for (int nj = 0; nj < 4; ++nj) {
        const int col = wc * 64 + nj * 16 + r16;
        const float bias_c = bias[col];
        #pragma unroll
        for (int mi = 0; mi < 4; ++mi) {
            const int rbase = wr * 64 + mi * 16 + q16 * 4;
            #pragma unroll
            for (int r = 0; r < 4; ++r)
                Asm[(rbase + r) * 132 + col] = bf16r(acc[mi][nj][r] + bias_c);
        }
    }
    __syncthreads();
    if (w == 1) {                      // K -> fp8 e4m3 plane, 128B rows
        #pragma unroll
        for (int i = 0; i < 8; ++i) {
            int g = tid + 256 * i;
            int m = g >> 4, c = g & 15;
            int row = rowBase + m;
            if (row < n) {
                uint4 d2 = *(const uint4*)&Asm[m * 132 + c * 8];
                float f[8];
                unpack8(d2, f);
                uint2 o;
                o.x = pk_fp8x4(f[0], f[1], f[2], f[3]);
                o.y = pk_fp8x4(f[4], f[5], f[6], f[7]);
                *(uint2*)(K8 + (size_t)row * 128 + c * 8) = o;
            }
        }
    } else {
        unsigned short* plane = (w == 0) ? Qp : (w == 2) ? Vp : Sp;
        #pragma unroll
        for (int i = 0; i < 8; ++i) {
            int g = tid + 256 * i;
            int m = g >> 4, c = g & 15;
            int row = rowBase + m;
            if (row < n) {
                uint4 d2 = *(const uint4*)&Asm[m * 132 + c * 8];
                *(uint4*)(plane + (size_t)row * 128 + c * 8) = d2;
            }
        }
    }
}

// ---------------------------------------------------------------------------
// CSR build. degree_hist saves each edge's rank; scatter is atomic-free.
// ---------------------------------------------------------------------------
__global__ void degree_hist(const int* __restrict__ dst, int e,
                            int* __restrict__ cnt, int* __restrict__ rank)
{
    int i = blockIdx.x * blockDim.x + threadIdx.x;
    if (i < e) rank[i] = atomicAdd(&cnt[dst[i]], 1);
}

__global__ __launch_bounds__(256)
void scan_hist(const int* __restrict__ cnt, int n, int* __restrict__ bsum, int* __restrict__ bh)
{
    __shared__ int sm[256];
    __shared__ int lh[64];
    if (threadIdx.x < 64) lh[threadIdx.x] = 0;
    int i = blockIdx.x * 256 + threadIdx.x;
    int v = (i < n) ? cnt[i] : 0;
    sm[threadIdx.x] = v;
    __syncthreads();
    if (i < n) atomicAdd(&lh[min(v, 63)], 1);
    #pragma unroll
    for (int off = 128; off > 0; off >>= 1) {
        if (threadIdx.x < off) sm[threadIdx.x] += sm[threadIdx.x + off];
        __syncthreads();
    }
    if (threadIdx.x == 0) bsum[blockIdx.x] = sm[0];
    if (threadIdx.x < 64 && lh[threadIdx.x] > 0)
        atomicAdd(&bh[threadIdx.x], lh[threadIdx.x]);
}

__global__ __launch_bounds__(256)
void scan2(int* __restrict__ bsum, int nb, const int* __restrict__ bh, int* __restrict__ boff)
{
    __shared__ int sm[256];
    int v = (threadIdx.x < nb) ? bsum[threadIdx.x] : 0;
    sm[threadIdx.x] = v;
    __syncthreads();
    int acc = v;
    for (int off = 1; off < 256; off <<= 1) {
        int t = (threadIdx.x >= off) ? sm[threadIdx.x - off] : 0;
        __syncthreads();
        acc += t;
        sm[threadIdx.x] = acc;
        __syncthreads();
    }
    if (threadIdx.x < nb) bsum[threadIdx.x] = acc - v;
    if (threadIdx.x == 0) {
        int run = 0;
        for (int b = 63; b >= 0; --b) { boff[b] = run; run += bh[b]; }
    }
}

__global__ __launch_bounds__(256)
void scan3_scatter(const int* __restrict__ cnt, const int* __restrict__ bsum,
                   int* __restrict__ row_ptr, int n, int e,
                   const int* __restrict__ boff, int* __restrict__ bcur,
                   int* __restrict__ perm)
{
    __shared__ int sm[256];
    __shared__ int lh[64];
    __shared__ int lbase[64];
    if (threadIdx.x < 64) lh[threadIdx.x] = 0;
    __syncthreads();
    int i = blockIdx.x * 256 + threadIdx.x;
    int v = (i < n) ? cnt[i] : 0;
    sm[threadIdx.x] = v;
    int b = 0, local = 0;
    if (i < n) {
        b = min(v, 63);
        local = atomicAdd(&lh[b], 1);
    }
    __syncthreads();
    int acc = v;
    for (int off = 1; off < 256; off <<= 1) {
        int t = (threadIdx.x >= off) ? sm[threadIdx.x - off] : 0;
        __syncthreads();
        acc += t;
        sm[threadIdx.x] = acc;
        __syncthreads();
    }
    if (i < n) row_ptr[i] = bsum[blockIdx.x] + acc - v;
    if (blockIdx.x == 0 && threadIdx.x == 0) row_ptr[n] = e;
    if (threadIdx.x < 64 && lh[threadIdx.x] > 0)
        lbase[threadIdx.x] = atomicAdd(&bcur[threadIdx.x], lh[threadIdx.x]);
    __syncthreads();
    if (i < n) perm[boff[b] + lbase[b] + local] = i;
}

// ---------------------------------------------------------------------------
// Attention helpers: 4-edge chunk, K fp8 (uint2/lane), V bf16 (uint4/lane).
// ---------------------------------------------------------------------------
__device__ inline void load4(const uint2* __restrict__ K8, const uint4* __restrict__ Vp,
                             const int* __restrict__ csr, int i, int l16,
                             uint2* k, uint4* v)
{
    int s0 = csr[i], s1 = csr[i+1], s2 = csr[i+2], s3 = csr[i+3];
    k[0] = K8[(size_t)s0 * 16 + l16];  v[0] = Vp[(size_t)s0 * 16 + l16];
    k[1] = K8[(size_t)s1 * 16 + l16];  v[1] = Vp[(size_t)s1 * 16 + l16];
    k[2] = K8[(size_t)s2 * 16 + l16];  v[2] = Vp[(size_t)s2 * 16 + l16];
    k[3] = K8[(size_t)s3 * 16 + l16];  v[3] = Vp[(size_t)s3 * 16 + l16];
}

__device__ inline void consume4(const uint2* k, const uint4* v, const float* q,
                                float& m, float& l, float* acc)
{
    float d0 = dot8_fp8(q, k[0]);
    float d1 = dot8_fp8(q, k[1]);
    float d2 = dot8_fp8(q, k[2]);
    float d3 = dot8_fp8(q, k[3]);

    d0 += __shfl_xor(d0, 4, 64); d1 += __shfl_xor(d1, 4, 64);
    d2 += __shfl_xor(d2, 4, 64); d3 += __shfl_xor(d3, 4, 64);
    d0 += __shfl_xor(d0, 2, 64); d1 += __shfl_xor(d1, 2, 64);
    d2 += __shfl_xor(d2, 2, 64); d3 += __shfl_xor(d3, 2, 64);
    d0 += __shfl_xor(d0, 1, 64); d1 += __shfl_xor(d1, 1, 64);
    d2 += __shfl_xor(d2, 1, 64); d3 += __shfl_xor(d3, 1, 64);

    float a0 = d0 * 0.125f, a1 = d1 * 0.125f, a2 = d2 * 0.125f, a3 = d3 * 0.125f;
    float m4 = fmaxf(fmaxf(a0, a1), fmaxf(a2, a3));
    float mn = fmaxf(m, m4);
    float corr = __expf(m - mn);
    float p0 = __expf(a0 - mn), p1 = __expf(a1 - mn);
    float p2 = __expf(a2 - mn), p3 = __expf(a3 - mn);
    l = l * corr + (p0 + p1 + p2 + p3);

    float v0f[8], v1f[8], v2f[8], v3f[8];
    unpack8(v[0], v0f); unpack8(v[1], v1f); unpack8(v[2], v2f); unpack8(v[3], v3f);
    #pragma unroll
    for (int c2 = 0; c2 < 8; ++c2) {
        float t = acc[c2] * corr;
        t += p0 * v0f[c2]; t += p1 * v1f[c2];
        t += p2 * v2f[c2]; t += p3 * v3f[c2];
        acc[c2] = t;
    }
    m = mn;
}

// ---------------------------------------------------------------------------
// Attention: 4 nodes/wave, 4-edge chunks, double-buffered.
// ---------------------------------------------------------------------------
__global__ __launch_bounds__(256)
void attn(const uint4* __restrict__ Qp, const uint2* __restrict__ K8,
          const uint4* __restrict__ Vp, const uint4* __restrict__ Sp,
          const int* __restrict__ row_ptr, const int* __restrict__ csr_src,
          const int* __restrict__ perm,
          float* __restrict__ outf, uint4* __restrict__ outb,
          int n, int do_relu)
{
    const int wid  = (blockIdx.x * 256 + threadIdx.x) >> 6;
    const int lane = threadIdx.x & 63;
    const int nq   = lane >> 4;
    const int l16  = lane & 15;
    const int nidx = wid * 4 + nq;
    const int node = (nidx < n) ? perm[nidx] : -1;

    float q[8];
    float sv[8];
    int beg = 0, end = 0;
    if (node >= 0) {
        uint4 qw = Qp[(size_t)node * 16 + l16];
        unpack8(qw, q);
        unpack8(Sp[(size_t)node * 16 + l16], sv);  // issued early, hides latency
        beg = row_ptr[node];
        end = row_ptr[node + 1];
    }

    float m = -INFINITY, l = 0.f;
    float acc[8] = {0.f, 0.f, 0.f, 0.f, 0.f, 0.f, 0.f, 0.f};

    int i = beg;
    uint2 ka[4], kb[4];
    uint4 va[4], vb[4];
    if (i + 4 <= end) load4(K8, Vp, csr_src, i, l16, ka, va);
    while (i + 8 <= end) {
        load4(K8, Vp, csr_src, i + 4, l16, kb, vb);
        consume4(ka, va, q, m, l, acc);
        i += 4;
        if (i + 8 <= end) {
            load4(K8, Vp, csr_src, i + 4, l16, ka, va);
            consume4(kb, vb, q, m, l, acc);
            i += 4;
        } else {
            #pragma unroll
            for (int t = 0; t < 4; ++t) { ka[t] = kb[t]; va[t] = vb[t]; }
        }
    }
    if (i + 4 <= end) {
        consume4(ka, va, q, m, l, acc);
        i += 4;
    }
    while (i < end) {                       // tail <=3 edges
        int s = csr_src[i];
        uint2 kw = K8[(size_t)s * 16 + l16];
        uint4 vw = Vp[(size_t)s * 16 + l16];
        float vf[8];
        unpack8(vw, vf);
        float part = dot8_fp8(q, kw);
        part += __shfl_xor(part, 4, 64);
        part += __shfl_xor(part, 2, 64);
        part += __shfl_xor(part, 1, 64);
        float alpha = part * 0.125f;
        float mn = fmaxf(m, alpha);
        float corr = __expf(m - mn);
        float p = __expf(alpha - mn);
        l = l * corr + p;
        #pragma unroll
        for (int c2 = 0; c2 < 8; ++c2) acc[c2] = acc[c2] * corr + p * vf[c2];
        m = mn;
        ++i;
    }

    if (node >= 0) {
        float inv = (l > 0.f) ? (1.f / l) : 0.f;
        float r[8];
        #pragma unroll
        for (int c2 = 0; c2 < 8; ++c2) r[c2] = acc[c2] * inv + sv[c2];
        if (do_relu) {
            #pragma unroll
            for (int c2 = 0; c2 < 8; ++c2) r[c2] = fmaxf(r[c2], 0.f);
        }
        if (outb) {
            uint4 o;
            o.x = bf16pair(r[0], r[1]); o.y = bf16pair(r[2], r[3]);
            o.z = bf16pair(r[4], r[5]); o.w = bf16pair(r[6], r[7]);
            outb[(size_t)node * 16 + l16] = o;
        } else {
            *(float4*)&outf[(size_t)node * 128 + l16 * 8]     = make_float4(r[0], r[1], r[2], r[3]);
            *(float4*)&outf[(size_t)node * 128 + l16 * 8 + 4] = make_float4(r[4], r[5], r[6], r[7]);
        }
    }
}

// ---------------------------------------------------------------------------
extern "C" void kernel_launch(void* const* d_in, const int* in_sizes, int n_in,
                              void* d_out, int out_size, void* d_ws, size_t ws_size,
                              hipStream_t stream)
{
    const float* x    = (const float*)d_in[0];
    const int*   edge = (const int*)d_in[1];
    const int n = in_sizes[0] / D;
    const int e = in_sizes[1] / 2;
    const int* srcv = edge;
    const int* dstv = edge + e;

    const float* Wq1 = (const float*)d_in[2];  const float* bq1 = (const float*)d_in[3];
    const float* Wk1 = (const float*)d_in[4];  const float* bk1 = (const float*)d_in[5];
    const float* Wv1 = (const float*)d_in[6];  const float* bv1 = (const float*)d_in[7];
    const float* Ws1 = (const float*)d_in[8];  const float* bs1 = (const float*)d_in[9];
    const float* Wq2 = (const float*)d_in[10]; const float* bq2 = (const float*)d_in[11];
    const float* Wk2 = (const float*)d_in[12]; const float* bk2 = (const float*)d_in[13];
    const float* Wv2 = (const float*)d_in[14]; const float* bv2 = (const float*)d_in[15];
    const float* Ws2 = (const float*)d_in[16]; const float* bs2 = (const float*)d_in[17];

    char* wsb = (char*)d_ws;
    size_t off = 0;
    auto alloc = [&](size_t bytes) -> void* {
        void* p = wsb + off;
        off += (bytes + 255) & ~(size_t)255;
        return p;
    };
    unsigned short* Qp = (unsigned short*)alloc((size_t)n * D * sizeof(unsigned short));
    unsigned char*  K8 = (unsigned char*)alloc((size_t)n * D);
    unsigned short* Vp = (unsigned short*)alloc((size_t)n * D * sizeof(unsigned short));
    unsigned short* Sp = (unsigned short*)alloc((size_t)n * D * sizeof(unsigned short));
    unsigned short* Xb = (unsigned short*)alloc((size_t)n * D * sizeof(unsigned short));
    unsigned short* Hu = (unsigned short*)alloc((size_t)n * D * sizeof(unsigned short));
    unsigned short* Wt = (unsigned short*)alloc(8 * 16384 * sizeof(unsigned short));
    int* cnt     = (int*)alloc((size_t)n * sizeof(int));
    int* row_ptr = (int*)alloc((size_t)(n + 1) * sizeof(int));
    int* bsum    = (int*)alloc(1024 * sizeof(int));
    int* perm    = (int*)alloc((size_t)n * sizeof(int));
    int* bh      = (int*)alloc(64 * sizeof(int));
    int* bcur    = (int*)alloc(64 * sizeof(int));
    int* boff    = (int*)alloc(64 * sizeof(int));
    int* rank    = (int*)alloc((size_t)e * sizeof(int));
    int* csr_src = (int*)alloc((size_t)e * sizeof(int));
    (void)ws_size; (void)n_in; (void)out_size;

    const int nb  = (n + 255) / 256;
    const int npairs = n * 64;
    const int nprep  = (npairs + 255) / 256 + nb + 8 + 1;

    prep<<<nprep, 256, 0, stream>>>(x, (unsigned*)Xb, npairs,
        Wq1, Wk1, Wv1, Ws1, Wq2, Wk2, Wv2, Ws2, Wt, cnt, bh, bcur, n);

    degree_hist<<<(e + 255) / 256, 256, 0, stream>>>(dstv, e, cnt, rank);
    scan_hist<<<nb, 256, 0, stream>>>(cnt, n, bsum, bh);
    scan2<<<1, 256, 0, stream>>>(bsum, nb, bh, boff);
    scan3_scatter<<<nb, 256, 0, stream>>>(cnt, bsum, row_ptr, n, e, boff, bcur, perm);

    const int gemmBlocks = 4 * ((n + 127) / 128);
    const int esBlocks   = (e + 255) / 256;
    const int ablocks = ((n + 3) / 4 + 3) / 4;

    // ---- layer 1 gemm fused with edge_scatter (independent work) ----
    gemm_es<<<gemmBlocks + esBlocks, 256, 0, stream>>>(Xb, n, Wt,
        bq1, bk1, bv1, bs1, Qp, K8, Vp, Sp, gemmBlocks,
        srcv, dstv, e, row_ptr, rank, csr_src);
    attn<<<ablocks, 256, 0, stream>>>((const uint4*)Qp, (const uint2*)K8, (const uint4*)Vp,
                                      (const uint4*)Sp, row_ptr, csr_src, perm,
                                      nullptr, (uint4*)Hu, n, 1);

    // ---- layer 2 (es part empty: e=0) ----
    gemm_es<<<gemmBlocks, 256, 0, stream>>>(Hu, n, Wt + 4 * 16384,
        bq2, bk2, bv2, bs2, Qp, K8, Vp, Sp, gemmBlocks,
        srcv, dstv, 0, row_ptr, rank, csr_src);
    attn<<<ablocks, 256, 0, stream>>>((const uint4*)Qp, (const uint2*)K8, (const uint4*)Vp,
                                      (const uint4*)Sp, row_ptr, csr_src, perm,
                                      (float*)d_out, nullptr, n, 0);
}

// Round 11
// 301.065 us; speedup vs baseline: 2.3495x; 1.0458x over previous
//
#include <hip/hip_runtime.h>
#include <math.h>

#define D 128

typedef float  f32x4  __attribute__((ext_vector_type(4)));
typedef float  f32x2  __attribute__((ext_vector_type(2)));
typedef short  bf16x8 __attribute__((ext_vector_type(8)));

__device__ inline unsigned short bf16r(float f) {
    unsigned u = __float_as_uint(f);
    u = (u + 0x7fff + ((u >> 16) & 1)) >> 16;
    return (unsigned short)u;
}
__device__ inline unsigned bf16pair(float a, float b) {
    return (unsigned)bf16r(a) | ((unsigned)bf16r(b) << 16);
}
__device__ inline float bf16lo(unsigned w) { return __uint_as_float(w << 16); }
__device__ inline float bf16hi(unsigned w) { return __uint_as_float(w & 0xffff0000u); }

__device__ inline void unpack8(uint4 w, float* f) {
    f[0] = bf16lo(w.x); f[1] = bf16hi(w.x);
    f[2] = bf16lo(w.y); f[3] = bf16hi(w.y);
    f[4] = bf16lo(w.z); f[5] = bf16hi(w.z);
    f[6] = bf16lo(w.w); f[7] = bf16hi(w.w);
}

// 4 floats -> 4 fp8 e4m3 packed in one dword (HW RNE)
__device__ inline unsigned pk_fp8x4(float a, float b, float c, float d) {
    unsigned w = 0;
    w = __builtin_amdgcn_cvt_pk_fp8_f32(a, b, w, false);
    w = __builtin_amdgcn_cvt_pk_fp8_f32(c, d, w, true);
    return w;
}

// dot of q[0..7] with 8 fp8 channels held in a uint2
__device__ inline float dot8_fp8(const float* q, uint2 kw) {
    f32x2 p;
    p = __builtin_amdgcn_cvt_pk_f32_fp8((int)kw.x, false);
    float s = q[0] * p.x + q[1] * p.y;
    p = __builtin_amdgcn_cvt_pk_f32_fp8((int)kw.x, true);
    s += q[2] * p.x + q[3] * p.y;
    p = __builtin_amdgcn_cvt_pk_f32_fp8((int)kw.y, false);
    s += q[4] * p.x + q[5] * p.y;
    p = __builtin_amdgcn_cvt_pk_f32_fp8((int)kw.y, true);
    s += q[6] * p.x + q[7] * p.y;
    return s;
}

// ---------------------------------------------------------------------------
// prep: fused convert_x + convert_w + zero(bh,bcur) + degree_hist.
// cnt must be zeroed (hipMemsetAsync) before this kernel.
// ---------------------------------------------------------------------------
__global__ __launch_bounds__(256)
void prep(const float* __restrict__ X, unsigned* __restrict__ Xb, int npairs,
          const float* __restrict__ W0, const float* __restrict__ W1,
          const float* __restrict__ W2, const float* __restrict__ W3,
          const float* __restrict__ W4, const float* __restrict__ W5,
          const float* __restrict__ W6, const float* __restrict__ W7,
          unsigned short* __restrict__ Wt,
          int* __restrict__ cnt, int* __restrict__ bh, int* __restrict__ bcur,
          const int* __restrict__ dstv, int e, int* __restrict__ rank)
{
    const int nxb = (npairs + 255) >> 8;
    const int b = blockIdx.x;
    if (b < nxb) {
        int i = b * 256 + threadIdx.x;
        if (i < npairs) {
            float2 v = *(const float2*)&X[2 * i];
            Xb[i] = bf16pair(v.x, v.y);
        }
    } else if (b < nxb + 8) {
        int wi = b - nxb;
        const float* Ws[8] = {W0, W1, W2, W3, W4, W5, W6, W7};
        const float* W = Ws[wi];
        unsigned short* o = Wt + wi * 16384;
        for (int i = threadIdx.x; i < 16384; i += 256) {
            int k = i >> 7, c = i & 127;
            o[c * 128 + k] = bf16r(W[i]);
        }
    } else if (b == nxb + 8) {
        if (threadIdx.x < 64) { bh[threadIdx.x] = 0; bcur[threadIdx.x] = 0; }
    } else {
        int i = (b - nxb - 9) * 256 + threadIdx.x;
        if (i < e) rank[i] = atomicAdd(&cnt[dstv[i]], 1);
    }
}

// ---------------------------------------------------------------------------
// Fused MFMA GEMM v3 + edge_scatter tail blocks.
// One block = 128 rows x ALL 4 weights: A-tile staged ONCE into LDS, looped
// over Q/K/V/S (4x MFMA per staging; Xb read once). Separate C-epilogue LDS
// buffer so A survives the loop. 69.6 KB LDS -> 2 blocks/CU (grid is only
// ~391 blocks ~ 1.5/CU, so residency is not the limiter).
// Outputs: Q,V,S bf16 planes; K fp8 e4m3 plane.
// ---------------------------------------------------------------------------
__global__ __launch_bounds__(256)
void gemm_es(const unsigned short* __restrict__ Xb, int n,
             const unsigned short* __restrict__ Wtall,
             const float* __restrict__ bq, const float* __restrict__ bk,
             const float* __restrict__ bv, const float* __restrict__ bs,
             unsigned short* __restrict__ Qp, unsigned char* __restrict__ K8,
             unsigned short* __restrict__ Vp, unsigned short* __restrict__ Sp,
             int gemmBlocks,
             const int* __restrict__ src, const int* __restrict__ dst, int e,
             const int* __restrict__ row_ptr, const int* __restrict__ rank,
             int* __restrict__ csr_src)
{
    const int bid = blockIdx.x;
    if (bid >= gemmBlocks) {           // -------- edge_scatter part --------
        int i = (bid - gemmBlocks) * 256 + threadIdx.x;
        if (i < e) {
            int d = dst[i];
            csr_src[row_ptr[d] + rank[i]] = src[i];   // atomic-free
        }
        return;
    }
    // ----------------------------- gemm part ------------------------------
    const int rowBase = bid * 128;

    __shared__ unsigned short Asm[128 * 136];
    __shared__ unsigned short Csm[128 * 132];

    const int tid  = threadIdx.x;
    const int wave = tid >> 6;
    const int lane = tid & 63;
    const int wr   = wave >> 1;
    const int wc   = wave & 1;
    const int q16  = lane >> 4;
    const int r16  = lane & 15;

    // stage A tile once
    #pragma unroll
    for (int i = 0; i < 8; ++i) {
        int g = tid + 256 * i;
        int m = g >> 4, c = g & 15;
        int row = rowBase + m; if (row >= n) row = n - 1;
        uint4 da = *(const uint4*)(Xb + (size_t)row * 128 + c * 8);
        *(uint4*)&Asm[m * 136 + c * 8] = da;
    }
    __syncthreads();

    for (int w = 0; w < 4; ++w) {
        const unsigned short* W = Wtall + w * 16384;
        const float* bias = (w == 0) ? bq : (w == 1) ? bk : (w == 2) ? bv : bs;
        const unsigned short* Wbase = W + (size_t)(wc * 64 + r16) * 128 + q16 * 8;

        f32x4 acc[4][4];
        #pragma unroll
        for (int mi = 0; mi < 4; ++mi)
            #pragma unroll
            for (int nj = 0; nj < 4; ++nj) acc[mi][nj] = (f32x4)(0.f);

        bf16x8 bcu[4], bnx[4];
        #pragma unroll
        for (int nj = 0; nj < 4; ++nj)
            bcu[nj] = *(const bf16x8*)(Wbase + nj * 16 * 128);

        #pragma unroll
        for (int kc = 0; kc < 4; ++kc) {
            if (kc < 3) {
                #pragma unroll
                for (int nj = 0; nj < 4; ++nj)
                    bnx[nj] = *(const bf16x8*)(Wbase + nj * 16 * 128 + (kc + 1) * 32);
            }
            bf16x8 a[4];
            #pragma unroll
            for (int mi = 0; mi < 4; ++mi)
                a[mi] = *(const bf16x8*)&Asm[(wr * 64 + mi * 16 + r16) * 136 + kc * 32 + q16 * 8];
            #pragma unroll
            for (int mi = 0; mi < 4; ++mi)
                #pragma unroll
                for (int nj = 0; nj < 4; ++nj)
                    acc[mi][nj] = __builtin_amdgcn_mfma_f32_16x16x32_bf16(a[mi], bcu[nj], acc[mi][nj], 0, 0, 0);
            #pragma unroll
            for (int nj = 0; nj < 4; ++nj) bcu[nj] = bnx[nj];
        }

        // epilogue: acc -> Csm (barrier-protected reuse) -> coalesced global
        __syncthreads();   // prior w's store loop finished reading Csm
        #pragma unroll
        for (int nj = 0; nj < 4; ++nj) {
            const int col = wc * 64 + nj * 16 + r16;
            const float bias_c = bias[col];
            #pragma unroll
            for (int mi = 0; mi < 4; ++mi) {
                const int rbase = wr * 64 + mi * 16 + q16 * 4;
                #pragma unroll
                for (int r = 0; r < 4; ++r)
                    Csm[(rbase + r) * 132 + col] = bf16r(acc[mi][nj][r] + bias_c);
            }
        }
        __syncthreads();
        if (w == 1) {                  // K -> fp8 e4m3 plane, 128B rows
            #pragma unroll
            for (int i = 0; i < 8; ++i) {
                int g = tid + 256 * i;
                int m = g >> 4, c = g & 15;
                int row = rowBase + m;
                if (row < n) {
                    uint4 d2 = *(const uint4*)&Csm[m * 132 + c * 8];
                    float f[8];
                    unpack8(d2, f);
                    uint2 o;
                    o.x = pk_fp8x4(f[0], f[1], f[2], f[3]);
                    o.y = pk_fp8x4(f[4], f[5], f[6], f[7]);
                    *(uint2*)(K8 + (size_t)row * 128 + c * 8) = o;
                }
            }
        } else {
            unsigned short* plane = (w == 0) ? Qp : (w == 2) ? Vp : Sp;
            #pragma unroll
            for (int i = 0; i < 8; ++i) {
                int g = tid + 256 * i;
                int m = g >> 4, c = g & 15;
                int row = rowBase + m;
                if (row < n) {
                    uint4 d2 = *(const uint4*)&Csm[m * 132 + c * 8];
                    *(uint4*)(plane + (size_t)row * 128 + c * 8) = d2;
                }
            }
        }
    }
}

// ---------------------------------------------------------------------------
// CSR scans (degree_hist now lives inside prep).
// ---------------------------------------------------------------------------
__global__ __launch_bounds__(256)
void scan_hist(const int* __restrict__ cnt, int n, int* __restrict__ bsum, int* __restrict__ bh)
{
    __shared__ int sm[256];
    __shared__ int lh[64];
    if (threadIdx.x < 64) lh[threadIdx.x] = 0;
    int i = blockIdx.x * 256 + threadIdx.x;
    int v = (i < n) ? cnt[i] : 0;
    sm[threadIdx.x] = v;
    __syncthreads();
    if (i < n) atomicAdd(&lh[min(v, 63)], 1);
    #pragma unroll
    for (int off = 128; off > 0; off >>= 1) {
        if (threadIdx.x < off) sm[threadIdx.x] += sm[threadIdx.x + off];
        __syncthreads();
    }
    if (threadIdx.x == 0) bsum[blockIdx.x] = sm[0];
    if (threadIdx.x < 64 && lh[threadIdx.x] > 0)
        atomicAdd(&bh[threadIdx.x], lh[threadIdx.x]);
}

__global__ __launch_bounds__(256)
void scan2(int* __restrict__ bsum, int nb, const int* __restrict__ bh, int* __restrict__ boff)
{
    __shared__ int sm[256];
    int v = (threadIdx.x < nb) ? bsum[threadIdx.x] : 0;
    sm[threadIdx.x] = v;
    __syncthreads();
    int acc = v;
    for (int off = 1; off < 256; off <<= 1) {
        int t = (threadIdx.x >= off) ? sm[threadIdx.x - off] : 0;
        __syncthreads();
        acc += t;
        sm[threadIdx.x] = acc;
        __syncthreads();
    }
    if (threadIdx.x < nb) bsum[threadIdx.x] = acc - v;
    if (threadIdx.x == 0) {
        int run = 0;
        for (int b = 63; b >= 0; --b) { boff[b] = run; run += bh[b]; }
    }
}

__global__ __launch_bounds__(256)
void scan3_scatter(const int* __restrict__ cnt, const int* __restrict__ bsum,
                   int* __restrict__ row_ptr, int n, int e,
                   const int* __restrict__ boff, int* __restrict__ bcur,
                   int* __restrict__ perm)
{
    __shared__ int sm[256];
    __shared__ int lh[64];
    __shared__ int lbase[64];
    if (threadIdx.x < 64) lh[threadIdx.x] = 0;
    __syncthreads();
    int i = blockIdx.x * 256 + threadIdx.x;
    int v = (i < n) ? cnt[i] : 0;
    sm[threadIdx.x] = v;
    int b = 0, local = 0;
    if (i < n) {
        b = min(v, 63);
        local = atomicAdd(&lh[b], 1);
    }
    __syncthreads();
    int acc = v;
    for (int off = 1; off < 256; off <<= 1) {
        int t = (threadIdx.x >= off) ? sm[threadIdx.x - off] : 0;
        __syncthreads();
        acc += t;
        sm[threadIdx.x] = acc;
        __syncthreads();
    }
    if (i < n) row_ptr[i] = bsum[blockIdx.x] + acc - v;
    if (blockIdx.x == 0 && threadIdx.x == 0) row_ptr[n] = e;
    if (threadIdx.x < 64 && lh[threadIdx.x] > 0)
        lbase[threadIdx.x] = atomicAdd(&bcur[threadIdx.x], lh[threadIdx.x]);
    __syncthreads();
    if (i < n) perm[boff[b] + lbase[b] + local] = i;
}

// ---------------------------------------------------------------------------
// Attention helpers: 4-edge chunk, K fp8 (uint2/lane), V bf16 (uint4/lane).
// ---------------------------------------------------------------------------
__device__ inline void load4(const uint2* __restrict__ K8, const uint4* __restrict__ Vp,
                             const int* __restrict__ csr, int i, int l16,
                             uint2* k, uint4* v)
{
    int s0 = csr[i], s1 = csr[i+1], s2 = csr[i+2], s3 = csr[i+3];
    k[0] = K8[(size_t)s0 * 16 + l16];  v[0] = Vp[(size_t)s0 * 16 + l16];
    k[1] = K8[(size_t)s1 * 16 + l16];  v[1] = Vp[(size_t)s1 * 16 + l16];
    k[2] = K8[(size_t)s2 * 16 + l16];  v[2] = Vp[(size_t)s2 * 16 + l16];
    k[3] = K8[(size_t)s3 * 16 + l16];  v[3] = Vp[(size_t)s3 * 16 + l16];
}

__device__ inline void consume4(const uint2* k, const uint4* v, const float* q,
                                float& m, float& l, float* acc)
{
    float d0 = dot8_fp8(q, k[0]);
    float d1 = dot8_fp8(q, k[1]);
    float d2 = dot8_fp8(q, k[2]);
    float d3 = dot8_fp8(q, k[3]);

    d0 += __shfl_xor(d0, 4, 64); d1 += __shfl_xor(d1, 4, 64);
    d2 += __shfl_xor(d2, 4, 64); d3 += __shfl_xor(d3, 4, 64);
    d0 += __shfl_xor(d0, 2, 64); d1 += __shfl_xor(d1, 2, 64);
    d2 += __shfl_xor(d2, 2, 64); d3 += __shfl_xor(d3, 2, 64);
    d0 += __shfl_xor(d0, 1, 64); d1 += __shfl_xor(d1, 1, 64);
    d2 += __shfl_xor(d2, 1, 64); d3 += __shfl_xor(d3, 1, 64);

    float a0 = d0 * 0.125f, a1 = d1 * 0.125f, a2 = d2 * 0.125f, a3 = d3 * 0.125f;
    float m4 = fmaxf(fmaxf(a0, a1), fmaxf(a2, a3));
    float mn = fmaxf(m, m4);
    float corr = __expf(m - mn);
    float p0 = __expf(a0 - mn), p1 = __expf(a1 - mn);
    float p2 = __expf(a2 - mn), p3 = __expf(a3 - mn);
    l = l * corr + (p0 + p1 + p2 + p3);

    float v0f[8], v1f[8], v2f[8], v3f[8];
    unpack8(v[0], v0f); unpack8(v[1], v1f); unpack8(v[2], v2f); unpack8(v[3], v3f);
    #pragma unroll
    for (int c2 = 0; c2 < 8; ++c2) {
        float t = acc[c2] * corr;
        t += p0 * v0f[c2]; t += p1 * v1f[c2];
        t += p2 * v2f[c2]; t += p3 * v3f[c2];
        acc[c2] = t;
    }
    m = mn;
}

// ---------------------------------------------------------------------------
// Attention: 4 nodes/wave, 4-edge chunks, double-buffered.
// ---------------------------------------------------------------------------
__global__ __launch_bounds__(256)
void attn(const uint4* __restrict__ Qp, const uint2* __restrict__ K8,
          const uint4* __restrict__ Vp, const uint4* __restrict__ Sp,
          const int* __restrict__ row_ptr, const int* __restrict__ csr_src,
          const int* __restrict__ perm,
          float* __restrict__ outf, uint4* __restrict__ outb,
          int n, int do_relu)
{
    const int wid  = (blockIdx.x * 256 + threadIdx.x) >> 6;
    const int lane = threadIdx.x & 63;
    const int nq   = lane >> 4;
    const int l16  = lane & 15;
    const int nidx = wid * 4 + nq;
    const int node = (nidx < n) ? perm[nidx] : -1;

    float q[8];
    float sv[8];
    int beg = 0, end = 0;
    if (node >= 0) {
        uint4 qw = Qp[(size_t)node * 16 + l16];
        unpack8(qw, q);
        unpack8(Sp[(size_t)node * 16 + l16], sv);
        beg = row_ptr[node];
        end = row_ptr[node + 1];
    }

    float m = -INFINITY, l = 0.f;
    float acc[8] = {0.f, 0.f, 0.f, 0.f, 0.f, 0.f, 0.f, 0.f};

    int i = beg;
    uint2 ka[4], kb[4];
    uint4 va[4], vb[4];
    if (i + 4 <= end) load4(K8, Vp, csr_src, i, l16, ka, va);
    while (i + 8 <= end) {
        load4(K8, Vp, csr_src, i + 4, l16, kb, vb);
        consume4(ka, va, q, m, l, acc);
        i += 4;
        if (i + 8 <= end) {
            load4(K8, Vp, csr_src, i + 4, l16, ka, va);
            consume4(kb, vb, q, m, l, acc);
            i += 4;
        } else {
            #pragma unroll
            for (int t = 0; t < 4; ++t) { ka[t] = kb[t]; va[t] = vb[t]; }
        }
    }
    if (i + 4 <= end) {
        consume4(ka, va, q, m, l, acc);
        i += 4;
    }
    while (i < end) {                       // tail <=3 edges
        int s = csr_src[i];
        uint2 kw = K8[(size_t)s * 16 + l16];
        uint4 vw = Vp[(size_t)s * 16 + l16];
        float vf[8];
        unpack8(vw, vf);
        float part = dot8_fp8(q, kw);
        part += __shfl_xor(part, 4, 64);
        part += __shfl_xor(part, 2, 64);
        part += __shfl_xor(part, 1, 64);
        float alpha = part * 0.125f;
        float mn = fmaxf(m, alpha);
        float corr = __expf(m - mn);
        float p = __expf(alpha - mn);
        l = l * corr + p;
        #pragma unroll
        for (int c2 = 0; c2 < 8; ++c2) acc[c2] = acc[c2] * corr + p * vf[c2];
        m = mn;
        ++i;
    }

    if (node >= 0) {
        float inv = (l > 0.f) ? (1.f / l) : 0.f;
        float r[8];
        #pragma unroll
        for (int c2 = 0; c2 < 8; ++c2) r[c2] = acc[c2] * inv + sv[c2];
        if (do_relu) {
            #pragma unroll
            for (int c2 = 0; c2 < 8; ++c2) r[c2] = fmaxf(r[c2], 0.f);
        }
        if (outb) {
            uint4 o;
            o.x = bf16pair(r[0], r[1]); o.y = bf16pair(r[2], r[3]);
            o.z = bf16pair(r[4], r[5]); o.w = bf16pair(r[6], r[7]);
            outb[(size_t)node * 16 + l16] = o;
        } else {
            *(float4*)&outf[(size_t)node * 128 + l16 * 8]     = make_float4(r[0], r[1], r[2], r[3]);
            *(float4*)&outf[(size_t)node * 128 + l16 * 8 + 4] = make_float4(r[4], r[5], r[6], r[7]);
        }
    }
}

// ---------------------------------------------------------------------------
extern "C" void kernel_launch(void* const* d_in, const int* in_sizes, int n_in,
                              void* d_out, int out_size, void* d_ws, size_t ws_size,
                              hipStream_t stream)
{
    const float* x    = (const float*)d_in[0];
    const int*   edge = (const int*)d_in[1];
    const int n = in_sizes[0] / D;
    const int e = in_sizes[1] / 2;
    const int* srcv = edge;
    const int* dstv = edge + e;

    const float* Wq1 = (const float*)d_in[2];  const float* bq1 = (const float*)d_in[3];
    const float* Wk1 = (const float*)d_in[4];  const float* bk1 = (const float*)d_in[5];
    const float* Wv1 = (const float*)d_in[6];  const float* bv1 = (const float*)d_in[7];
    const float* Ws1 = (const float*)d_in[8];  const float* bs1 = (const float*)d_in[9];
    const float* Wq2 = (const float*)d_in[10]; const float* bq2 = (const float*)d_in[11];
    const float* Wk2 = (const float*)d_in[12]; const float* bk2 = (const float*)d_in[13];
    const float* Wv2 = (const float*)d_in[14]; const float* bv2 = (const float*)d_in[15];
    const float* Ws2 = (const float*)d_in[16]; const float* bs2 = (const float*)d_in[17];

    char* wsb = (char*)d_ws;
    size_t off = 0;
    auto alloc = [&](size_t bytes) -> void* {
        void* p = wsb + off;
        off += (bytes + 255) & ~(size_t)255;
        return p;
    };
    unsigned short* Qp = (unsigned short*)alloc((size_t)n * D * sizeof(unsigned short));
    unsigned char*  K8 = (unsigned char*)alloc((size_t)n * D);
    unsigned short* Vp = (unsigned short*)alloc((size_t)n * D * sizeof(unsigned short));
    unsigned short* Sp = (unsigned short*)alloc((size_t)n * D * sizeof(unsigned short));
    unsigned short* Xb = (unsigned short*)alloc((size_t)n * D * sizeof(unsigned short));
    unsigned short* Hu = (unsigned short*)alloc((size_t)n * D * sizeof(unsigned short));
    unsigned short* Wt = (unsigned short*)alloc(8 * 16384 * sizeof(unsigned short));
    int* cnt     = (int*)alloc((size_t)n * sizeof(int));
    int* row_ptr = (int*)alloc((size_t)(n + 1) * sizeof(int));
    int* bsum    = (int*)alloc(1024 * sizeof(int));
    int* perm    = (int*)alloc((size_t)n * sizeof(int));
    int* bh      = (int*)alloc(64 * sizeof(int));
    int* bcur    = (int*)alloc(64 * sizeof(int));
    int* boff    = (int*)alloc(64 * sizeof(int));
    int* rank    = (int*)alloc((size_t)e * sizeof(int));
    int* csr_src = (int*)alloc((size_t)e * sizeof(int));
    (void)ws_size; (void)n_in; (void)out_size;

    const int nb  = (n + 255) / 256;
    const int npairs = n * 64;
    const int eb  = (e + 255) / 256;
    const int nprep = (npairs + 255) / 256 + 8 + 1 + eb;

    // cnt=0, then prep (converts + bh/bcur zero + degree_hist blocks)
    hipMemsetAsync(cnt, 0, (size_t)n * sizeof(int), stream);
    prep<<<nprep, 256, 0, stream>>>(x, (unsigned*)Xb, npairs,
        Wq1, Wk1, Wv1, Ws1, Wq2, Wk2, Wv2, Ws2, Wt, cnt, bh, bcur,
        dstv, e, rank);

    scan_hist<<<nb, 256, 0, stream>>>(cnt, n, bsum, bh);
    scan2<<<1, 256, 0, stream>>>(bsum, nb, bh, boff);
    scan3_scatter<<<nb, 256, 0, stream>>>(cnt, bsum, row_ptr, n, e, boff, bcur, perm);

    const int gemmBlocks = (n + 127) / 128;
    const int ablocks = ((n + 3) / 4 + 3) / 4;

    // ---- layer 1 gemm fused with edge_scatter (independent work) ----
    gemm_es<<<gemmBlocks + eb, 256, 0, stream>>>(Xb, n, Wt,
        bq1, bk1, bv1, bs1, Qp, K8, Vp, Sp, gemmBlocks,
        srcv, dstv, e, row_ptr, rank, csr_src);
    attn<<<ablocks, 256, 0, stream>>>((const uint4*)Qp, (const uint2*)K8, (const uint4*)Vp,
                                      (const uint4*)Sp, row_ptr, csr_src, perm,
                                      nullptr, (uint4*)Hu, n, 1);

    // ---- layer 2 (es part empty: e=0) ----
    gemm_es<<<gemmBlocks, 256, 0, stream>>>(Hu, n, Wt + 4 * 16384,
        bq2, bk2, bv2, bs2, Qp, K8, Vp, Sp, gemmBlocks,
        srcv, dstv, 0, row_ptr, rank, csr_src);
    attn<<<ablocks, 256, 0, stream>>>((const uint4*)Qp, (const uint2*)K8, (const uint4*)Vp,
                                      (const uint4*)Sp, row_ptr, csr_src, perm,
                                      (float*)d_out, nullptr, n, 0);
}

// Round 12
// 295.309 us; speedup vs baseline: 2.3953x; 1.0195x over previous
//
#include <hip/hip_runtime.h>
#include <math.h>

#define D 128

typedef float  f32x4  __attribute__((ext_vector_type(4)));
typedef float  f32x2  __attribute__((ext_vector_type(2)));
typedef short  bf16x8 __attribute__((ext_vector_type(8)));

__device__ inline unsigned short bf16r(float f) {
    unsigned u = __float_as_uint(f);
    u = (u + 0x7fff + ((u >> 16) & 1)) >> 16;
    return (unsigned short)u;
}
__device__ inline unsigned bf16pair(float a, float b) {
    return (unsigned)bf16r(a) | ((unsigned)bf16r(b) << 16);
}
__device__ inline float bf16lo(unsigned w) { return __uint_as_float(w << 16); }
__device__ inline float bf16hi(unsigned w) { return __uint_as_float(w & 0xffff0000u); }

__device__ inline void unpack8(uint4 w, float* f) {
    f[0] = bf16lo(w.x); f[1] = bf16hi(w.x);
    f[2] = bf16lo(w.y); f[3] = bf16hi(w.y);
    f[4] = bf16lo(w.z); f[5] = bf16hi(w.z);
    f[6] = bf16lo(w.w); f[7] = bf16hi(w.w);
}

// 4 floats -> 4 fp8 e4m3 packed in one dword (HW RNE)
__device__ inline unsigned pk_fp8x4(float a, float b, float c, float d) {
    unsigned w = 0;
    w = __builtin_amdgcn_cvt_pk_fp8_f32(a, b, w, false);
    w = __builtin_amdgcn_cvt_pk_fp8_f32(c, d, w, true);
    return w;
}

// dot of q[0..7] with 8 fp8 channels held in a uint2
__device__ inline float dot8_fp8(const float* q, uint2 kw) {
    f32x2 p;
    p = __builtin_amdgcn_cvt_pk_f32_fp8((int)kw.x, false);
    float s = q[0] * p.x + q[1] * p.y;
    p = __builtin_amdgcn_cvt_pk_f32_fp8((int)kw.x, true);
    s += q[2] * p.x + q[3] * p.y;
    p = __builtin_amdgcn_cvt_pk_f32_fp8((int)kw.y, false);
    s += q[4] * p.x + q[5] * p.y;
    p = __builtin_amdgcn_cvt_pk_f32_fp8((int)kw.y, true);
    s += q[6] * p.x + q[7] * p.y;
    return s;
}

// ---------------------------------------------------------------------------
// prep: fused convert_x + convert_w + zero(bh,bcur) + sharded degree_hist.
// cnt8[8][n] must be zeroed before this kernel. Hist blocks handle 1024 edges
// each and atomic into shard (hb&7): 8x less same-line contention, 4
// atomic-returns in flight per thread.
// ---------------------------------------------------------------------------
__global__ __launch_bounds__(256)
void prep(const float* __restrict__ X, unsigned* __restrict__ Xb, int npairs,
          const float* __restrict__ W0, const float* __restrict__ W1,
          const float* __restrict__ W2, const float* __restrict__ W3,
          const float* __restrict__ W4, const float* __restrict__ W5,
          const float* __restrict__ W6, const float* __restrict__ W7,
          unsigned short* __restrict__ Wt,
          int* __restrict__ cnt8, int* __restrict__ bh, int* __restrict__ bcur,
          const int* __restrict__ dstv, int e, int* __restrict__ rank, int n)
{
    const int nxb = (npairs + 255) >> 8;
    const int b = blockIdx.x;
    if (b < nxb) {
        int i = b * 256 + threadIdx.x;
        if (i < npairs) {
            float2 v = *(const float2*)&X[2 * i];
            Xb[i] = bf16pair(v.x, v.y);
        }
    } else if (b < nxb + 8) {
        int wi = b - nxb;
        const float* Ws[8] = {W0, W1, W2, W3, W4, W5, W6, W7};
        const float* W = Ws[wi];
        unsigned short* o = Wt + wi * 16384;
        for (int i = threadIdx.x; i < 16384; i += 256) {
            int k = i >> 7, c = i & 127;
            o[c * 128 + k] = bf16r(W[i]);
        }
    } else if (b == nxb + 8) {
        if (threadIdx.x < 64) { bh[threadIdx.x] = 0; bcur[threadIdx.x] = 0; }
    } else {
        int hb = b - nxb - 9;                    // hist block: 1024 edges
        int* cs = cnt8 + (size_t)(hb & 7) * n;   // shard plane
        int base = hb * 1024 + threadIdx.x;
        #pragma unroll
        for (int u = 0; u < 4; ++u) {
            int i = base + u * 256;
            if (i < e) rank[i] = atomicAdd(&cs[dstv[i]], 1);
        }
    }
}

// ---------------------------------------------------------------------------
// Fused MFMA GEMM + edge_scatter tail blocks.
// One block = 128 rows x ALL 4 weights (A-tile staged once, Xb read once).
// Outputs: Q,V,S bf16 planes; K fp8 e4m3 plane.
// ---------------------------------------------------------------------------
__global__ __launch_bounds__(256)
void gemm_es(const unsigned short* __restrict__ Xb, int n,
             const unsigned short* __restrict__ Wtall,
             const float* __restrict__ bq, const float* __restrict__ bk,
             const float* __restrict__ bv, const float* __restrict__ bs,
             unsigned short* __restrict__ Qp, unsigned char* __restrict__ K8,
             unsigned short* __restrict__ Vp, unsigned short* __restrict__ Sp,
             int gemmBlocks,
             const int* __restrict__ src, const int* __restrict__ dst, int e,
             const int* __restrict__ row_ptr, const int* __restrict__ rank,
             const int* __restrict__ sbase,
             int* __restrict__ csr_src)
{
    const int bid = blockIdx.x;
    if (bid >= gemmBlocks) {           // -------- edge_scatter part --------
        int i = (bid - gemmBlocks) * 256 + threadIdx.x;
        if (i < e) {
            int d = dst[i];
            int shard = (i >> 10) & 7;
            csr_src[row_ptr[d] + sbase[(size_t)shard * n + d] + rank[i]] = src[i];
        }
        return;
    }
    // ----------------------------- gemm part ------------------------------
    const int rowBase = bid * 128;

    __shared__ unsigned short Asm[128 * 136];
    __shared__ unsigned short Csm[128 * 132];

    const int tid  = threadIdx.x;
    const int wave = tid >> 6;
    const int lane = tid & 63;
    const int wr   = wave >> 1;
    const int wc   = wave & 1;
    const int q16  = lane >> 4;
    const int r16  = lane & 15;

    #pragma unroll
    for (int i = 0; i < 8; ++i) {
        int g = tid + 256 * i;
        int m = g >> 4, c = g & 15;
        int row = rowBase + m; if (row >= n) row = n - 1;
        uint4 da = *(const uint4*)(Xb + (size_t)row * 128 + c * 8);
        *(uint4*)&Asm[m * 136 + c * 8] = da;
    }
    __syncthreads();

    for (int w = 0; w < 4; ++w) {
        const unsigned short* W = Wtall + w * 16384;
        const float* bias = (w == 0) ? bq : (w == 1) ? bk : (w == 2) ? bv : bs;
        const unsigned short* Wbase = W + (size_t)(wc * 64 + r16) * 128 + q16 * 8;

        f32x4 acc[4][4];
        #pragma unroll
        for (int mi = 0; mi < 4; ++mi)
            #pragma unroll
            for (int nj = 0; nj < 4; ++nj) acc[mi][nj] = (f32x4)(0.f);

        bf16x8 bcu[4], bnx[4];
        #pragma unroll
        for (int nj = 0; nj < 4; ++nj)
            bcu[nj] = *(const bf16x8*)(Wbase + nj * 16 * 128);

        #pragma unroll
        for (int kc = 0; kc < 4; ++kc) {
            if (kc < 3) {
                #pragma unroll
                for (int nj = 0; nj < 4; ++nj)
                    bnx[nj] = *(const bf16x8*)(Wbase + nj * 16 * 128 + (kc + 1) * 32);
            }
            bf16x8 a[4];
            #pragma unroll
            for (int mi = 0; mi < 4; ++mi)
                a[mi] = *(const bf16x8*)&Asm[(wr * 64 + mi * 16 + r16) * 136 + kc * 32 + q16 * 8];
            #pragma unroll
            for (int mi = 0; mi < 4; ++mi)
                #pragma unroll
                for (int nj = 0; nj < 4; ++nj)
                    acc[mi][nj] = __builtin_amdgcn_mfma_f32_16x16x32_bf16(a[mi], bcu[nj], acc[mi][nj], 0, 0, 0);
            #pragma unroll
            for (int nj = 0; nj < 4; ++nj) bcu[nj] = bnx[nj];
        }

        __syncthreads();   // prior w's store loop finished reading Csm
        #pragma unroll
        for (int nj = 0; nj < 4; ++nj) {
            const int col = wc * 64 + nj * 16 + r16;
            const float bias_c = bias[col];
            #pragma unroll
            for (int mi = 0; mi < 4; ++mi) {
                const int rbase = wr * 64 + mi * 16 + q16 * 4;
                #pragma unroll
                for (int r = 0; r < 4; ++r)
                    Csm[(rbase + r) * 132 + col] = bf16r(acc[mi][nj][r] + bias_c);
            }
        }
        __syncthreads();
        if (w == 1) {                  // K -> fp8 e4m3 plane, 128B rows
            #pragma unroll
            for (int i = 0; i < 8; ++i) {
                int g = tid + 256 * i;
                int m = g >> 4, c = g & 15;
                int row = rowBase + m;
                if (row < n) {
                    uint4 d2 = *(const uint4*)&Csm[m * 132 + c * 8];
                    float f[8];
                    unpack8(d2, f);
                    uint2 o;
                    o.x = pk_fp8x4(f[0], f[1], f[2], f[3]);
                    o.y = pk_fp8x4(f[4], f[5], f[6], f[7]);
                    *(uint2*)(K8 + (size_t)row * 128 + c * 8) = o;
                }
            }
        } else {
            unsigned short* plane = (w == 0) ? Qp : (w == 2) ? Vp : Sp;
            #pragma unroll
            for (int i = 0; i < 8; ++i) {
                int g = tid + 256 * i;
                int m = g >> 4, c = g & 15;
                int row = rowBase + m;
                if (row < n) {
                    uint4 d2 = *(const uint4*)&Csm[m * 132 + c * 8];
                    *(uint4*)(plane + (size_t)row * 128 + c * 8) = d2;
                }
            }
        }
    }
}

// ---------------------------------------------------------------------------
// scan_hist: per node, sum the 8 shard counts -> total degree; emit per-shard
// exclusive bases (sbase) and total (cnt_tot); block-sum for row_ptr scan and
// degree-bucket histogram as before.
// ---------------------------------------------------------------------------
__global__ __launch_bounds__(256)
void scan_hist(const int* __restrict__ cnt8, int n, int* __restrict__ bsum,
               int* __restrict__ bh, int* __restrict__ sbase, int* __restrict__ cnt_tot)
{
    __shared__ int sm[256];
    __shared__ int lh[64];
    if (threadIdx.x < 64) lh[threadIdx.x] = 0;
    int i = blockIdx.x * 256 + threadIdx.x;
    int v = 0;
    if (i < n) {
        int run = 0;
        #pragma unroll
        for (int s = 0; s < 8; ++s) {
            int c = cnt8[(size_t)s * n + i];
            sbase[(size_t)s * n + i] = run;
            run += c;
        }
        v = run;
        cnt_tot[i] = v;
    }
    sm[threadIdx.x] = v;
    __syncthreads();
    if (i < n) atomicAdd(&lh[min(v, 63)], 1);
    #pragma unroll
    for (int off = 128; off > 0; off >>= 1) {
        if (threadIdx.x < off) sm[threadIdx.x] += sm[threadIdx.x + off];
        __syncthreads();
    }
    if (threadIdx.x == 0) bsum[blockIdx.x] = sm[0];
    if (threadIdx.x < 64 && lh[threadIdx.x] > 0)
        atomicAdd(&bh[threadIdx.x], lh[threadIdx.x]);
}

__global__ __launch_bounds__(256)
void scan2(int* __restrict__ bsum, int nb, const int* __restrict__ bh, int* __restrict__ boff)
{
    __shared__ int sm[256];
    int v = (threadIdx.x < nb) ? bsum[threadIdx.x] : 0;
    sm[threadIdx.x] = v;
    __syncthreads();
    int acc = v;
    for (int off = 1; off < 256; off <<= 1) {
        int t = (threadIdx.x >= off) ? sm[threadIdx.x - off] : 0;
        __syncthreads();
        acc += t;
        sm[threadIdx.x] = acc;
        __syncthreads();
    }
    if (threadIdx.x < nb) bsum[threadIdx.x] = acc - v;
    if (threadIdx.x == 0) {
        int run = 0;
        for (int b = 63; b >= 0; --b) { boff[b] = run; run += bh[b]; }
    }
}

__global__ __launch_bounds__(256)
void scan3_scatter(const int* __restrict__ cnt_tot, const int* __restrict__ bsum,
                   int* __restrict__ row_ptr, int n, int e,
                   const int* __restrict__ boff, int* __restrict__ bcur,
                   int* __restrict__ perm)
{
    __shared__ int sm[256];
    __shared__ int lh[64];
    __shared__ int lbase[64];
    if (threadIdx.x < 64) lh[threadIdx.x] = 0;
    __syncthreads();
    int i = blockIdx.x * 256 + threadIdx.x;
    int v = (i < n) ? cnt_tot[i] : 0;
    sm[threadIdx.x] = v;
    int b = 0, local = 0;
    if (i < n) {
        b = min(v, 63);
        local = atomicAdd(&lh[b], 1);
    }
    __syncthreads();
    int acc = v;
    for (int off = 1; off < 256; off <<= 1) {
        int t = (threadIdx.x >= off) ? sm[threadIdx.x - off] : 0;
        __syncthreads();
        acc += t;
        sm[threadIdx.x] = acc;
        __syncthreads();
    }
    if (i < n) row_ptr[i] = bsum[blockIdx.x] + acc - v;
    if (blockIdx.x == 0 && threadIdx.x == 0) row_ptr[n] = e;
    if (threadIdx.x < 64 && lh[threadIdx.x] > 0)
        lbase[threadIdx.x] = atomicAdd(&bcur[threadIdx.x], lh[threadIdx.x]);
    __syncthreads();
    if (i < n) perm[boff[b] + lbase[b] + local] = i;
}

// ---------------------------------------------------------------------------
// Attention helpers: 4-edge chunk, K fp8 (uint2/lane), V bf16 (uint4/lane).
// ---------------------------------------------------------------------------
__device__ inline void load4(const uint2* __restrict__ K8, const uint4* __restrict__ Vp,
                             const int* __restrict__ csr, int i, int l16,
                             uint2* k, uint4* v)
{
    int s0 = csr[i], s1 = csr[i+1], s2 = csr[i+2], s3 = csr[i+3];
    k[0] = K8[(size_t)s0 * 16 + l16];  v[0] = Vp[(size_t)s0 * 16 + l16];
    k[1] = K8[(size_t)s1 * 16 + l16];  v[1] = Vp[(size_t)s1 * 16 + l16];
    k[2] = K8[(size_t)s2 * 16 + l16];  v[2] = Vp[(size_t)s2 * 16 + l16];
    k[3] = K8[(size_t)s3 * 16 + l16];  v[3] = Vp[(size_t)s3 * 16 + l16];
}

__device__ inline void consume4(const uint2* k, const uint4* v, const float* q,
                                float& m, float& l, float* acc)
{
    float d0 = dot8_fp8(q, k[0]);
    float d1 = dot8_fp8(q, k[1]);
    float d2 = dot8_fp8(q, k[2]);
    float d3 = dot8_fp8(q, k[3]);

    d0 += __shfl_xor(d0, 4, 64); d1 += __shfl_xor(d1, 4, 64);
    d2 += __shfl_xor(d2, 4, 64); d3 += __shfl_xor(d3, 4, 64);
    d0 += __shfl_xor(d0, 2, 64); d1 += __shfl_xor(d1, 2, 64);
    d2 += __shfl_xor(d2, 2, 64); d3 += __shfl_xor(d3, 2, 64);
    d0 += __shfl_xor(d0, 1, 64); d1 += __shfl_xor(d1, 1, 64);
    d2 += __shfl_xor(d2, 1, 64); d3 += __shfl_xor(d3, 1, 64);

    float a0 = d0 * 0.125f, a1 = d1 * 0.125f, a2 = d2 * 0.125f, a3 = d3 * 0.125f;
    float m4 = fmaxf(fmaxf(a0, a1), fmaxf(a2, a3));
    float mn = fmaxf(m, m4);
    float corr = __expf(m - mn);
    float p0 = __expf(a0 - mn), p1 = __expf(a1 - mn);
    float p2 = __expf(a2 - mn), p3 = __expf(a3 - mn);
    l = l * corr + (p0 + p1 + p2 + p3);

    float v0f[8], v1f[8], v2f[8], v3f[8];
    unpack8(v[0], v0f); unpack8(v[1], v1f); unpack8(v[2], v2f); unpack8(v[3], v3f);
    #pragma unroll
    for (int c2 = 0; c2 < 8; ++c2) {
        float t = acc[c2] * corr;
        t += p0 * v0f[c2]; t += p1 * v1f[c2];
        t += p2 * v2f[c2]; t += p3 * v3f[c2];
        acc[c2] = t;
    }
    m = mn;
}

// ---------------------------------------------------------------------------
// Attention: 4 nodes/wave, 4-edge chunks, double-buffered.
// ---------------------------------------------------------------------------
__global__ __launch_bounds__(256)
void attn(const uint4* __restrict__ Qp, const uint2* __restrict__ K8,
          const uint4* __restrict__ Vp, const uint4* __restrict__ Sp,
          const int* __restrict__ row_ptr, const int* __restrict__ csr_src,
          const int* __restrict__ perm,
          float* __restrict__ outf, uint4* __restrict__ outb,
          int n, int do_relu)
{
    const int wid  = (blockIdx.x * 256 + threadIdx.x) >> 6;
    const int lane = threadIdx.x & 63;
    const int nq   = lane >> 4;
    const int l16  = lane & 15;
    const int nidx = wid * 4 + nq;
    const int node = (nidx < n) ? perm[nidx] : -1;

    float q[8];
    float sv[8];
    int beg = 0, end = 0;
    if (node >= 0) {
        uint4 qw = Qp[(size_t)node * 16 + l16];
        unpack8(qw, q);
        unpack8(Sp[(size_t)node * 16 + l16], sv);
        beg = row_ptr[node];
        end = row_ptr[node + 1];
    }

    float m = -INFINITY, l = 0.f;
    float acc[8] = {0.f, 0.f, 0.f, 0.f, 0.f, 0.f, 0.f, 0.f};

    int i = beg;
    uint2 ka[4], kb[4];
    uint4 va[4], vb[4];
    if (i + 4 <= end) load4(K8, Vp, csr_src, i, l16, ka, va);
    while (i + 8 <= end) {
        load4(K8, Vp, csr_src, i + 4, l16, kb, vb);
        consume4(ka, va, q, m, l, acc);
        i += 4;
        if (i + 8 <= end) {
            load4(K8, Vp, csr_src, i + 4, l16, ka, va);
            consume4(kb, vb, q, m, l, acc);
            i += 4;
        } else {
            #pragma unroll
            for (int t = 0; t < 4; ++t) { ka[t] = kb[t]; va[t] = vb[t]; }
        }
    }
    if (i + 4 <= end) {
        consume4(ka, va, q, m, l, acc);
        i += 4;
    }
    while (i < end) {                       // tail <=3 edges
        int s = csr_src[i];
        uint2 kw = K8[(size_t)s * 16 + l16];
        uint4 vw = Vp[(size_t)s * 16 + l16];
        float vf[8];
        unpack8(vw, vf);
        float part = dot8_fp8(q, kw);
        part += __shfl_xor(part, 4, 64);
        part += __shfl_xor(part, 2, 64);
        part += __shfl_xor(part, 1, 64);
        float alpha = part * 0.125f;
        float mn = fmaxf(m, alpha);
        float corr = __expf(m - mn);
        float p = __expf(alpha - mn);
        l = l * corr + p;
        #pragma unroll
        for (int c2 = 0; c2 < 8; ++c2) acc[c2] = acc[c2] * corr + p * vf[c2];
        m = mn;
        ++i;
    }

    if (node >= 0) {
        float inv = (l > 0.f) ? (1.f / l) : 0.f;
        float r[8];
        #pragma unroll
        for (int c2 = 0; c2 < 8; ++c2) r[c2] = acc[c2] * inv + sv[c2];
        if (do_relu) {
            #pragma unroll
            for (int c2 = 0; c2 < 8; ++c2) r[c2] = fmaxf(r[c2], 0.f);
        }
        if (outb) {
            uint4 o;
            o.x = bf16pair(r[0], r[1]); o.y = bf16pair(r[2], r[3]);
            o.z = bf16pair(r[4], r[5]); o.w = bf16pair(r[6], r[7]);
            outb[(size_t)node * 16 + l16] = o;
        } else {
            *(float4*)&outf[(size_t)node * 128 + l16 * 8]     = make_float4(r[0], r[1], r[2], r[3]);
            *(float4*)&outf[(size_t)node * 128 + l16 * 8 + 4] = make_float4(r[4], r[5], r[6], r[7]);
        }
    }
}

// ---------------------------------------------------------------------------
extern "C" void kernel_launch(void* const* d_in, const int* in_sizes, int n_in,
                              void* d_out, int out_size, void* d_ws, size_t ws_size,
                              hipStream_t stream)
{
    const float* x    = (const float*)d_in[0];
    const int*   edge = (const int*)d_in[1];
    const int n = in_sizes[0] / D;
    const int e = in_sizes[1] / 2;
    const int* srcv = edge;
    const int* dstv = edge + e;

    const float* Wq1 = (const float*)d_in[2];  const float* bq1 = (const float*)d_in[3];
    const float* Wk1 = (const float*)d_in[4];  const float* bk1 = (const float*)d_in[5];
    const float* Wv1 = (const float*)d_in[6];  const float* bv1 = (const float*)d_in[7];
    const float* Ws1 = (const float*)d_in[8];  const float* bs1 = (const float*)d_in[9];
    const float* Wq2 = (const float*)d_in[10]; const float* bq2 = (const float*)d_in[11];
    const float* Wk2 = (const float*)d_in[12]; const float* bk2 = (const float*)d_in[13];
    const float* Wv2 = (const float*)d_in[14]; const float* bv2 = (const float*)d_in[15];
    const float* Ws2 = (const float*)d_in[16]; const float* bs2 = (const float*)d_in[17];

    char* wsb = (char*)d_ws;
    size_t off = 0;
    auto alloc = [&](size_t bytes) -> void* {
        void* p = wsb + off;
        off += (bytes + 255) & ~(size_t)255;
        return p;
    };
    unsigned short* Qp = (unsigned short*)alloc((size_t)n * D * sizeof(unsigned short));
    unsigned char*  K8 = (unsigned char*)alloc((size_t)n * D);
    unsigned short* Vp = (unsigned short*)alloc((size_t)n * D * sizeof(unsigned short));
    unsigned short* Sp = (unsigned short*)alloc((size_t)n * D * sizeof(unsigned short));
    unsigned short* Xb = (unsigned short*)alloc((size_t)n * D * sizeof(unsigned short));
    unsigned short* Hu = (unsigned short*)alloc((size_t)n * D * sizeof(unsigned short));
    unsigned short* Wt = (unsigned short*)alloc(8 * 16384 * sizeof(unsigned short));
    int* cnt8    = (int*)alloc((size_t)8 * n * sizeof(int));
    int* sbase   = (int*)alloc((size_t)8 * n * sizeof(int));
    int* cnt_tot = (int*)alloc((size_t)n * sizeof(int));
    int* row_ptr = (int*)alloc((size_t)(n + 1) * sizeof(int));
    int* bsum    = (int*)alloc(1024 * sizeof(int));
    int* perm    = (int*)alloc((size_t)n * sizeof(int));
    int* bh      = (int*)alloc(64 * sizeof(int));
    int* bcur    = (int*)alloc(64 * sizeof(int));
    int* boff    = (int*)alloc(64 * sizeof(int));
    int* rank    = (int*)alloc((size_t)e * sizeof(int));
    int* csr_src = (int*)alloc((size_t)e * sizeof(int));
    (void)ws_size; (void)n_in; (void)out_size;

    const int nb  = (n + 255) / 256;
    const int npairs = n * 64;
    const int eb   = (e + 255) / 256;
    const int hb   = (e + 1023) / 1024;
    const int nprep = (npairs + 255) / 256 + 8 + 1 + hb;

    // zero shard counters, then prep (converts + bh/bcur zero + sharded hist)
    hipMemsetAsync(cnt8, 0, (size_t)8 * n * sizeof(int), stream);
    prep<<<nprep, 256, 0, stream>>>(x, (unsigned*)Xb, npairs,
        Wq1, Wk1, Wv1, Ws1, Wq2, Wk2, Wv2, Ws2, Wt, cnt8, bh, bcur,
        dstv, e, rank, n);

    scan_hist<<<nb, 256, 0, stream>>>(cnt8, n, bsum, bh, sbase, cnt_tot);
    scan2<<<1, 256, 0, stream>>>(bsum, nb, bh, boff);
    scan3_scatter<<<nb, 256, 0, stream>>>(cnt_tot, bsum, row_ptr, n, e, boff, bcur, perm);

    const int gemmBlocks = (n + 127) / 128;
    const int ablocks = ((n + 3) / 4 + 3) / 4;

    // ---- layer 1 gemm fused with edge_scatter (independent work) ----
    gemm_es<<<gemmBlocks + eb, 256, 0, stream>>>(Xb, n, Wt,
        bq1, bk1, bv1, bs1, Qp, K8, Vp, Sp, gemmBlocks,
        srcv, dstv, e, row_ptr, rank, sbase, csr_src);
    attn<<<ablocks, 256, 0, stream>>>((const uint4*)Qp, (const uint2*)K8, (const uint4*)Vp,
                                      (const uint4*)Sp, row_ptr, csr_src, perm,
                                      nullptr, (uint4*)Hu, n, 1);

    // ---- layer 2 (es part empty: e=0) ----
    gemm_es<<<gemmBlocks, 256, 0, stream>>>(Hu, n, Wt + 4 * 16384,
        bq2, bk2, bv2, bs2, Qp, K8, Vp, Sp, gemmBlocks,
        srcv, dstv, 0, row_ptr, rank, sbase, csr_src);
    attn<<<ablocks, 256, 0, stream>>>((const uint4*)Qp, (const uint2*)K8, (const uint4*)Vp,
                                      (const uint4*)Sp, row_ptr, csr_src, perm,
                                      (float*)d_out, nullptr, n, 0);
}